// Round 8
// baseline (516.592 us; speedup 1.0000x reference)
//
#include <hip/hip_runtime.h>

// ---------------------------------------------------------------------------
// Weight transpose: w[o][c][k] -> wT[(k*ci + c)*co + o]  (o contiguous so the
// compute kernel's uniform weight reads merge into s_load_dwordx4/x8).
// ---------------------------------------------------------------------------
struct WtArgs { const float* src[6]; int co[6], ci[6], k2[6], dstoff[6]; };

__global__ __launch_bounds__(256)
void transpose_weights(WtArgs a, float* __restrict__ dst0)
{
    const int L = blockIdx.x;
    const float* __restrict__ s = a.src[L];
    float* __restrict__ d = dst0 + a.dstoff[L];
    const int co = a.co[L], ci = a.ci[L], k2 = a.k2[L];
    const int n = co * ci * k2;
    for (int i = threadIdx.x; i < n; i += 256) {
        int k = i % k2;
        int c = (i / k2) % ci;
        int o = i / (k2 * ci);
        d[(k * ci + c) * co + o] = s[i];
    }
}

// ---------------------------------------------------------------------------
// Round-6 proven kernel (used for L1, L2, L5, L6): image staged channel-inner
// with padded stride S; wave-aligned k-groups; SGPR weight streams.
// ---------------------------------------------------------------------------
template<int CIN, int COUT, int K, int H, int W, int HO, int WO,
         int S, int KSEG, int NT>
__global__ __launch_bounds__(NT)
void deform_lds(const float* __restrict__ x, const float* __restrict__ off,
                const float* __restrict__ wT, const float* __restrict__ bias,
                float* __restrict__ y)
{
    constexpr int K2 = K * K, HW = H * W, P = HO * WO;
    constexpr int PW = ((P + 63) / 64) * 64;
    constexpr int KLEN = (K2 + KSEG - 1) / KSEG;
    constexpr int PSTR = (COUT % 2 == 0) ? COUT + 1 : COUT;
    static_assert(NT >= KSEG * PW, "NT too small for KSEG*PW");

    __shared__ __align__(16) float simg[HW * S];
    __shared__ float part[(KSEG > 1) ? (KSEG - 1) * P * PSTR : 1];

    const int tid = threadIdx.x;
    const int b   = blockIdx.x;

    const float* xb = x + (size_t)b * CIN * HW;
    for (int i = tid; i < CIN * HW; i += NT) {
        int c = i / HW, hw = i - c * HW;
        simg[hw * S + c] = xb[i];
    }
    __syncthreads();

    const int g  = tid / PW;
    const int p  = tid - g * PW;
    const int pc = (p < P) ? p : (P - 1);
    const bool active = (p < P);

    float acc[COUT];
#pragma unroll
    for (int o = 0; o < COUT; ++o) acc[o] = 0.f;

    if (g < KSEG) {
        if (g == 0) {
#pragma unroll
            for (int o = 0; o < COUT; ++o) acc[o] = bias[o];
        }
        const int ho = pc / WO, wo = pc - ho * WO;
        const int kb = g * KLEN;

        const int kf = (kb < K2) ? kb : (K2 - 1);
        float ndy = off[(2 * kf)     * P + pc];
        float ndx = off[(2 * kf + 1) * P + pc];

#pragma unroll 1
        for (int j = 0; j < KLEN; ++j) {
            const int k  = kb + j;
            const int kk = (k < K2) ? k : (K2 - 1);
            const float dy = ndy, dx = ndx;
            const int kn = (k + 1 < K2) ? (k + 1) : (K2 - 1);
            ndy = off[(2 * kn)     * P + pc];
            ndx = off[(2 * kn + 1) * P + pc];

            const int ky = kk / K, kx = kk - ky * K;
            const float py = (float)(ho + ky) + dy;
            const float px = (float)(wo + kx) + dx;
            const float y0f = floorf(py), x0f = floorf(px);
            const float wy = py - y0f, wx = px - x0f;
            const int y0 = (int)y0f, x0 = (int)x0f;
            const int y1 = y0 + 1,  x1 = x0 + 1;
            const bool vy0 = ((unsigned)y0 < (unsigned)H);
            const bool vy1 = ((unsigned)y1 < (unsigned)H);
            const bool vx0 = ((unsigned)x0 < (unsigned)W);
            const bool vx1 = ((unsigned)x1 < (unsigned)W);
            const int cy0 = min(max(y0, 0), H - 1) * W;
            const int cy1 = min(max(y1, 0), H - 1) * W;
            const int cx0 = min(max(x0, 0), W - 1);
            const int cx1 = min(max(x1, 0), W - 1);
            float w00 = (vy0 && vx0) ? (1.f - wy) * (1.f - wx) : 0.f;
            float w01 = (vy0 && vx1) ? (1.f - wy) * wx         : 0.f;
            float w10 = (vy1 && vx0) ? wy * (1.f - wx)         : 0.f;
            float w11 = (vy1 && vx1) ? wy * wx                 : 0.f;
            if constexpr (K2 % KSEG != 0) {
                const float kv = (k < K2) ? 1.f : 0.f;
                w00 *= kv; w01 *= kv; w10 *= kv; w11 *= kv;
            }

            const float* __restrict__ r00 = simg + (cy0 + cx0) * S;
            const float* __restrict__ r01 = simg + (cy0 + cx1) * S;
            const float* __restrict__ r10 = simg + (cy1 + cx0) * S;
            const float* __restrict__ r11 = simg + (cy1 + cx1) * S;
            const int kku = __builtin_amdgcn_readfirstlane(kk);
            const float* __restrict__ wk = wT + kku * (CIN * COUT);

            if constexpr (CIN % 4 == 0) {
#pragma unroll
                for (int c4 = 0; c4 < CIN / 4; ++c4) {
                    const float4 v00 = *(const float4*)(r00 + c4 * 4);
                    const float4 v01 = *(const float4*)(r01 + c4 * 4);
                    const float4 v10 = *(const float4*)(r10 + c4 * 4);
                    const float4 v11 = *(const float4*)(r11 + c4 * 4);
                    float4 sa;
                    sa.x = fmaf(w00, v00.x, fmaf(w01, v01.x, fmaf(w10, v10.x, w11 * v11.x)));
                    sa.y = fmaf(w00, v00.y, fmaf(w01, v01.y, fmaf(w10, v10.y, w11 * v11.y)));
                    sa.z = fmaf(w00, v00.z, fmaf(w01, v01.z, fmaf(w10, v10.z, w11 * v11.z)));
                    sa.w = fmaf(w00, v00.w, fmaf(w01, v01.w, fmaf(w10, v10.w, w11 * v11.w)));
                    const float* __restrict__ wc = wk + (c4 * 4) * COUT;
#pragma unroll
                    for (int o = 0; o < COUT; ++o) acc[o] = fmaf(wc[o], sa.x, acc[o]);
#pragma unroll
                    for (int o = 0; o < COUT; ++o) acc[o] = fmaf(wc[COUT + o], sa.y, acc[o]);
#pragma unroll
                    for (int o = 0; o < COUT; ++o) acc[o] = fmaf(wc[2 * COUT + o], sa.z, acc[o]);
#pragma unroll
                    for (int o = 0; o < COUT; ++o) acc[o] = fmaf(wc[3 * COUT + o], sa.w, acc[o]);
                }
            } else {
#pragma unroll
                for (int c = 0; c < CIN; ++c) {
                    float sa = fmaf(w00, r00[c], fmaf(w01, r01[c],
                               fmaf(w10, r10[c], w11 * r11[c])));
#pragma unroll
                    for (int o = 0; o < COUT; ++o)
                        acc[o] = fmaf(wk[c * COUT + o], sa, acc[o]);
                }
            }
        }

        if (g > 0 && active) {
#pragma unroll
            for (int o = 0; o < COUT; ++o)
                part[(g - 1) * (P * PSTR) + p * PSTR + o] = acc[o];
        }
    }

    if constexpr (KSEG > 1) __syncthreads();

    if (g == 0 && active) {
        if constexpr (KSEG > 1) {
#pragma unroll
            for (int gg = 1; gg < KSEG; ++gg)
#pragma unroll
                for (int o = 0; o < COUT; ++o)
                    acc[o] += part[(gg - 1) * (P * PSTR) + p * PSTR + o];
        }
        float* yb = y + (size_t)b * COUT * P;
#pragma unroll
        for (int o = 0; o < COUT; ++o)
            yb[o * P + p] = fmaxf(acc[o], 0.f);
    }
}

// ---------------------------------------------------------------------------
// deform3 (L3/L4): k-segments x sequential pixel-phases. Only ONE acc[COUT]
// live at a time (no spills). Compact float4 [c4][hw] LDS image. Partials
// accumulated into a bias-initialized LDS out-buffer via uniform-barrier
// sequenced adds (deterministic).
// ---------------------------------------------------------------------------
template<int CIN, int COUT, int K, int H, int W, int HO, int WO,
         int KSEG, int NPH, int NT>
__global__ __launch_bounds__(NT)
void deform3(const float* __restrict__ x, const float* __restrict__ off,
             const float* __restrict__ wT, const float* __restrict__ bias,
             float* __restrict__ y)
{
    constexpr int K2 = K * K, HW = H * W, P = HO * WO;
    constexpr int PH = (P + NPH - 1) / NPH;
    constexpr int PW = ((PH + 63) / 64) * 64;
    constexpr int KLEN = (K2 + KSEG - 1) / KSEG;
    constexpr int PSTR = (COUT % 2 == 0) ? COUT + 1 : COUT;
    constexpr int C4 = CIN / 4;
    static_assert(CIN % 4 == 0, "deform3 needs CIN%4==0");
    static_assert(KSEG * PW == NT, "exact fit required");

    __shared__ __align__(16) float4 simg4[C4 * HW];
    __shared__ float outb[P * PSTR];

    const int tid = threadIdx.x;
    const int b   = blockIdx.x;

    // stage image: [c][hw] -> float4 groups [c4][hw]
    {
        float* sf = (float*)simg4;
        const float* xb = x + (size_t)b * CIN * HW;
        for (int i = tid; i < CIN * HW; i += NT) {
            int c = i / HW, hw = i - c * HW;
            sf[((c >> 2) * HW + hw) * 4 + (c & 3)] = xb[i];
        }
    }
    // init out-buffer with bias
    for (int i = tid; i < P * COUT; i += NT) {
        int p = i / COUT, o = i - p * COUT;
        outb[p * PSTR + o] = bias[o];
    }
    __syncthreads();

    const int g = tid / PW;               // wave-uniform k-segment id
    const int q = tid - g * PW;           // phase-pixel index
    const int kb = g * KLEN;

#pragma unroll 1
    for (int ph = 0; ph < NPH; ++ph) {
        const int p  = q + ph * PH;
        const bool active = (q < PH) && (p < P);
        const int pc = active ? p : 0;
        const int ho = pc / WO, wo = pc - ho * WO;

        float acc[COUT];
#pragma unroll
        for (int o = 0; o < COUT; ++o) acc[o] = 0.f;

        const int kf = (kb < K2) ? kb : (K2 - 1);
        float ndy = off[(2 * kf)     * P + pc];
        float ndx = off[(2 * kf + 1) * P + pc];

#pragma unroll 1
        for (int j = 0; j < KLEN; ++j) {
            const int k  = kb + j;                    // wave-uniform
            const int kk = (k < K2) ? k : (K2 - 1);
            const float dy = ndy, dx = ndx;
            const int kn = (k + 1 < K2) ? (k + 1) : (K2 - 1);
            ndy = off[(2 * kn)     * P + pc];
            ndx = off[(2 * kn + 1) * P + pc];

            const int ky = kk / K, kx = kk - ky * K;
            const float py = (float)(ho + ky) + dy;
            const float px = (float)(wo + kx) + dx;
            const float y0f = floorf(py), x0f = floorf(px);
            const float wy = py - y0f, wx = px - x0f;
            const int y0 = (int)y0f, x0 = (int)x0f;
            const int y1 = y0 + 1,  x1 = x0 + 1;
            const bool vy0 = ((unsigned)y0 < (unsigned)H);
            const bool vy1 = ((unsigned)y1 < (unsigned)H);
            const bool vx0 = ((unsigned)x0 < (unsigned)W);
            const bool vx1 = ((unsigned)x1 < (unsigned)W);
            const int cy0 = min(max(y0, 0), H - 1) * W;
            const int cy1 = min(max(y1, 0), H - 1) * W;
            const int cx0 = min(max(x0, 0), W - 1);
            const int cx1 = min(max(x1, 0), W - 1);
            float w00 = (vy0 && vx0) ? (1.f - wy) * (1.f - wx) : 0.f;
            float w01 = (vy0 && vx1) ? (1.f - wy) * wx         : 0.f;
            float w10 = (vy1 && vx0) ? wy * (1.f - wx)         : 0.f;
            float w11 = (vy1 && vx1) ? wy * wx                 : 0.f;
            if constexpr (K2 % KSEG != 0) {
                const float kv = (k < K2) ? 1.f : 0.f;   // masked tail
                w00 *= kv; w01 *= kv; w10 *= kv; w11 *= kv;
            }
            const int i00 = cy0 + cx0, i01 = cy0 + cx1;
            const int i10 = cy1 + cx0, i11 = cy1 + cx1;

            const int kku = __builtin_amdgcn_readfirstlane(kk);
            const float* __restrict__ wk = wT + kku * (CIN * COUT);

#pragma unroll
            for (int c4 = 0; c4 < C4; ++c4) {
                const float4 v00 = simg4[c4 * HW + i00];
                const float4 v01 = simg4[c4 * HW + i01];
                const float4 v10 = simg4[c4 * HW + i10];
                const float4 v11 = simg4[c4 * HW + i11];
                float4 sa;
                sa.x = fmaf(w00, v00.x, fmaf(w01, v01.x, fmaf(w10, v10.x, w11 * v11.x)));
                sa.y = fmaf(w00, v00.y, fmaf(w01, v01.y, fmaf(w10, v10.y, w11 * v11.y)));
                sa.z = fmaf(w00, v00.z, fmaf(w01, v01.z, fmaf(w10, v10.z, w11 * v11.z)));
                sa.w = fmaf(w00, v00.w, fmaf(w01, v01.w, fmaf(w10, v10.w, w11 * v11.w)));
                const float* __restrict__ wc = wk + (c4 * 4) * COUT;
#pragma unroll
                for (int o = 0; o < COUT; ++o) acc[o] = fmaf(wc[o], sa.x, acc[o]);
#pragma unroll
                for (int o = 0; o < COUT; ++o) acc[o] = fmaf(wc[COUT + o], sa.y, acc[o]);
#pragma unroll
                for (int o = 0; o < COUT; ++o) acc[o] = fmaf(wc[2 * COUT + o], sa.z, acc[o]);
#pragma unroll
                for (int o = 0; o < COUT; ++o) acc[o] = fmaf(wc[3 * COUT + o], sa.w, acc[o]);
            }
        }

        // deterministic sequenced accumulation (uniform barriers)
        for (int gg = 0; gg < KSEG; ++gg) {
            if (g == gg && active) {
#pragma unroll
                for (int o = 0; o < COUT; ++o)
                    outb[p * PSTR + o] += acc[o];
            }
            __syncthreads();
        }
    }

    // store with ReLU
    float* yb = y + (size_t)b * COUT * P;
    for (int i = tid; i < COUT * P; i += NT) {
        int o = i / P, p = i - o * P;
        yb[i] = fmaxf(outb[p * PSTR + o], 0.f);
    }
}

// ---------------------------------------------------------------------------
// Fused head: perm gather + FC(676->256) + ReLU + FC(256->10).
// ---------------------------------------------------------------------------
__global__ __launch_bounds__(256)
void fc_head(const float* __restrict__ x6, const float* __restrict__ w7,
             const float* __restrict__ b7, const float* __restrict__ w8,
             const float* __restrict__ b8, const int* __restrict__ perm,
             float* __restrict__ out)
{
    constexpr int BPB = 4;
    constexpr int F   = 676;
    __shared__ float sx[BPB][F];
    __shared__ float sh[BPB][256];

    const int tid = threadIdx.x;
    const int b0  = blockIdx.x * BPB;

    for (int i = tid; i < BPB * F; i += 256) {
        int bb = i / F, f = i - bb * F;
        int c = f / 169, p = f - c * 169;
        sx[bb][f] = x6[(size_t)(b0 + bb) * F + c * 169 + perm[p]];
    }
    __syncthreads();

    float acc[BPB];
#pragma unroll
    for (int bb = 0; bb < BPB; ++bb) acc[bb] = b7[tid];
#pragma unroll 4
    for (int i = 0; i < F; ++i) {
        const float wv = w7[i * 256 + tid];
#pragma unroll
        for (int bb = 0; bb < BPB; ++bb)
            acc[bb] = fmaf(sx[bb][i], wv, acc[bb]);
    }
#pragma unroll
    for (int bb = 0; bb < BPB; ++bb) sh[bb][tid] = fmaxf(acc[bb], 0.f);
    __syncthreads();

    if (tid < BPB * 10) {
        int bb = tid / 10, t = tid - bb * 10;
        float a = b8[t];
#pragma unroll 8
        for (int j = 0; j < 256; ++j)
            a = fmaf(sh[bb][j], w8[j * 10 + t], a);
        out[(size_t)(b0 + bb) * 10 + t] = a;
    }
}

// ---------------------------------------------------------------------------
extern "C" void kernel_launch(void* const* d_in, const int* in_sizes, int n_in,
                              void* d_out, int out_size, void* d_ws, size_t ws_size,
                              hipStream_t stream)
{
    const float* x    = (const float*)d_in[0];
    const float* off1 = (const float*)d_in[1];
    const float* w1   = (const float*)d_in[2];
    const float* b1   = (const float*)d_in[3];
    const float* off2 = (const float*)d_in[4];
    const float* w2   = (const float*)d_in[5];
    const float* b2   = (const float*)d_in[6];
    const float* off3 = (const float*)d_in[7];
    const float* w3   = (const float*)d_in[8];
    const float* b3   = (const float*)d_in[9];
    const float* off4 = (const float*)d_in[10];
    const float* w4   = (const float*)d_in[11];
    const float* b4   = (const float*)d_in[12];
    const float* off5 = (const float*)d_in[13];
    const float* w5   = (const float*)d_in[14];
    const float* b5   = (const float*)d_in[15];
    const float* off6 = (const float*)d_in[16];
    const float* w6   = (const float*)d_in[17];
    const float* b6   = (const float*)d_in[18];
    const float* w7   = (const float*)d_in[19];
    const float* b7   = (const float*)d_in[20];
    const float* w8   = (const float*)d_in[21];
    const float* b8   = (const float*)d_in[22];
    const int*   perm = (const int*)d_in[23];
    float* out = (float*)d_out;

    // ws layout (floats), identical footprint to the proven layout:
    const int woff[6] = {0, 144, 4752, 17552, 30096, 33296};
    float* ws   = (float*)d_ws;
    float* wt   = ws;
    float* buf0 = ws + 33792;
    float* buf1 = buf0 + 3936256;

    float* a1 = buf0;   // 256*16*961
    float* a2 = buf1;   // 256*32*841
    float* a3 = buf0;   // 256*16*625
    float* a4 = buf1;   // 256*16*361
    float* a5 = buf0;   // 256*8*225
    float* a6 = buf1;   // 256*4*169

    WtArgs wa;
    wa.src[0] = w1; wa.src[1] = w2; wa.src[2] = w3;
    wa.src[3] = w4; wa.src[4] = w5; wa.src[5] = w6;
    const int cos[6] = {16, 32, 16, 16, 8, 4};
    const int cis[6] = {1, 16, 32, 16, 16, 8};
    const int k2s[6] = {9, 9, 25, 49, 25, 9};
    for (int i = 0; i < 6; ++i) {
        wa.co[i] = cos[i]; wa.ci[i] = cis[i];
        wa.k2[i] = k2s[i]; wa.dstoff[i] = woff[i];
    }
    transpose_weights<<<dim3(6), dim3(256), 0, stream>>>(wa, wt);

    const dim3 grid(256);
    // L1,L2,L5,L6: round-6 proven configs <CIN,COUT,K,H,W,HO,WO,S,KSEG,NT>
    deform_lds< 1, 16, 3, 33, 33, 31, 31,  1, 1, 1024><<<grid, dim3(1024), 0, stream>>>(x,  off1, wt + woff[0], b1, a1);
    deform_lds<16, 32, 3, 31, 31, 29, 29, 20, 1, 1024><<<grid, dim3(1024), 0, stream>>>(a1, off2, wt + woff[1], b2, a2);
    // L3,L4: deform3 <CIN,COUT,K,H,W,HO,WO,KSEG,NPH,NT>
    deform3<32, 16, 5, 29, 29, 25, 25, 3, 2, 960><<<grid, dim3(960), 0, stream>>>(a2, off3, wt + woff[2], b3, a3);
    deform3<16, 16, 7, 25, 25, 19, 19, 5, 2, 960><<<grid, dim3(960), 0, stream>>>(a3, off4, wt + woff[3], b4, a4);
    deform_lds<16,  8, 5, 19, 19, 15, 15, 20, 4, 1024><<<grid, dim3(1024), 0, stream>>>(a4, off5, wt + woff[4], b5, a5);
    deform_lds< 8,  4, 3, 15, 15, 13, 13, 12, 5,  960><<<grid, dim3(960),  0, stream>>>(a5, off6, wt + woff[5], b6, a6);

    fc_head<<<dim3(64), dim3(256), 0, stream>>>(a6, w7, b7, w8, b8, perm, out);
}

// Round 9
// 279.790 us; speedup vs baseline: 1.8464x; 1.8464x over previous
//
#include <hip/hip_runtime.h>

// ---------------------------------------------------------------------------
// Weight transpose: w[o][c][k] -> wT[(k*ci + c)*co + o]  (o contiguous so the
// compute kernel's uniform weight reads merge into s_load_dwordx4/x8).
// ---------------------------------------------------------------------------
struct WtArgs { const float* src[6]; int co[6], ci[6], k2[6], dstoff[6]; };

__global__ __launch_bounds__(256)
void transpose_weights(WtArgs a, float* __restrict__ dst0)
{
    const int L = blockIdx.x;
    const float* __restrict__ s = a.src[L];
    float* __restrict__ d = dst0 + a.dstoff[L];
    const int co = a.co[L], ci = a.ci[L], k2 = a.k2[L];
    const int n = co * ci * k2;
    for (int i = threadIdx.x; i < n; i += 256) {
        int k = i % k2;
        int c = (i / k2) % ci;
        int o = i / (k2 * ci);
        d[(k * ci + c) * co + o] = s[i];
    }
}

// ---------------------------------------------------------------------------
// Round-6 proven deformable conv kernel, extended with two orthogonal flags:
//  COMB:     staging reads relu(x0[i]+x1[i]) (consumer-side combine of a split
//            producer's partial sums) instead of x0[i].
//  SPLITOUT: this launch is one half of a channel-split producer:
//            grid (B, 2); blockIdx.y = h selects channels [h*CIN .. h*CIN+CIN)
//            of a CINW-channel input; bias added only for h==0; stores RAW
//            partial sums (no relu) to y + h*pstride.
// Otherwise byte-identical logic to the proven round-6 kernel.
// x layout: [B][CINW][H*W]   y: [B][COUT][HO*WO] (per half-buffer if split)
// ---------------------------------------------------------------------------
template<int CIN, int CINW, int COUT, int K, int H, int W, int HO, int WO,
         int S, int KSEG, int NT, bool COMB, bool SPLITOUT>
__global__ __launch_bounds__(NT)
void deform_lds(const float* __restrict__ x0, const float* __restrict__ x1,
                const float* __restrict__ off, const float* __restrict__ wT,
                const float* __restrict__ bias, float* __restrict__ y,
                size_t pstride)
{
    constexpr int K2 = K * K, HW = H * W, P = HO * WO;
    constexpr int PW = ((P + 63) / 64) * 64;
    constexpr int KLEN = (K2 + KSEG - 1) / KSEG;
    constexpr int PSTR = (COUT % 2 == 0) ? COUT + 1 : COUT;
    static_assert(NT >= KSEG * PW, "NT too small for KSEG*PW");

    __shared__ __align__(16) float simg[HW * S];
    __shared__ float part[(KSEG > 1) ? (KSEG - 1) * P * PSTR : 1];

    const int tid = threadIdx.x;
    const int b   = blockIdx.x;
    const int h   = SPLITOUT ? blockIdx.y : 0;

    // ---- stage image (channel-inner, padded stride S) ----
    const size_t xoff = (size_t)b * CINW * HW + (SPLITOUT ? (size_t)h * CIN * HW : 0);
    const float* xb  = x0 + xoff;
    const float* xb1 = COMB ? (x1 + xoff) : nullptr;
    for (int i = tid; i < CIN * HW; i += NT) {
        int c = i / HW, hw = i - c * HW;
        float v;
        if constexpr (COMB) v = fmaxf(xb[i] + xb1[i], 0.f);
        else                v = xb[i];
        simg[hw * S + c] = v;
    }
    __syncthreads();

    const int g  = tid / PW;
    const int p  = tid - g * PW;
    const int pc = (p < P) ? p : (P - 1);
    const bool active = (p < P);

    float acc[COUT];
#pragma unroll
    for (int o = 0; o < COUT; ++o) acc[o] = 0.f;

    if (g < KSEG) {
        if (g == 0 && (!SPLITOUT || h == 0)) {
#pragma unroll
            for (int o = 0; o < COUT; ++o) acc[o] = bias[o];
        }
        const int ho = pc / WO, wo = pc - ho * WO;
        const int kb = g * KLEN;

        const int kf = (kb < K2) ? kb : (K2 - 1);
        float ndy = off[(2 * kf)     * P + pc];
        float ndx = off[(2 * kf + 1) * P + pc];

#pragma unroll 1
        for (int j = 0; j < KLEN; ++j) {
            const int k  = kb + j;
            const int kk = (k < K2) ? k : (K2 - 1);
            const float dy = ndy, dx = ndx;
            const int kn = (k + 1 < K2) ? (k + 1) : (K2 - 1);
            ndy = off[(2 * kn)     * P + pc];
            ndx = off[(2 * kn + 1) * P + pc];

            const int ky = kk / K, kx = kk - ky * K;
            const float py = (float)(ho + ky) + dy;
            const float px = (float)(wo + kx) + dx;
            const float y0f = floorf(py), x0f = floorf(px);
            const float wy = py - y0f, wx = px - x0f;
            const int y0 = (int)y0f, x0 = (int)x0f;
            const int y1 = y0 + 1,  x1i = x0 + 1;
            const bool vy0 = ((unsigned)y0  < (unsigned)H);
            const bool vy1 = ((unsigned)y1  < (unsigned)H);
            const bool vx0 = ((unsigned)x0  < (unsigned)W);
            const bool vx1 = ((unsigned)x1i < (unsigned)W);
            const int cy0 = min(max(y0, 0), H - 1) * W;
            const int cy1 = min(max(y1, 0), H - 1) * W;
            const int cx0 = min(max(x0, 0), W - 1);
            const int cx1 = min(max(x1i, 0), W - 1);
            float w00 = (vy0 && vx0) ? (1.f - wy) * (1.f - wx) : 0.f;
            float w01 = (vy0 && vx1) ? (1.f - wy) * wx         : 0.f;
            float w10 = (vy1 && vx0) ? wy * (1.f - wx)         : 0.f;
            float w11 = (vy1 && vx1) ? wy * wx                 : 0.f;
            if constexpr (K2 % KSEG != 0) {
                const float kv = (k < K2) ? 1.f : 0.f;
                w00 *= kv; w01 *= kv; w10 *= kv; w11 *= kv;
            }

            const float* __restrict__ r00 = simg + (cy0 + cx0) * S;
            const float* __restrict__ r01 = simg + (cy0 + cx1) * S;
            const float* __restrict__ r10 = simg + (cy1 + cx0) * S;
            const float* __restrict__ r11 = simg + (cy1 + cx1) * S;
            const int kku = __builtin_amdgcn_readfirstlane(kk);
            const float* __restrict__ wk = wT + kku * (CINW * COUT)
                                         + (SPLITOUT ? h * (CIN * COUT) : 0);

            if constexpr (CIN % 4 == 0) {
#pragma unroll
                for (int c4 = 0; c4 < CIN / 4; ++c4) {
                    const float4 v00 = *(const float4*)(r00 + c4 * 4);
                    const float4 v01 = *(const float4*)(r01 + c4 * 4);
                    const float4 v10 = *(const float4*)(r10 + c4 * 4);
                    const float4 v11 = *(const float4*)(r11 + c4 * 4);
                    float4 sa;
                    sa.x = fmaf(w00, v00.x, fmaf(w01, v01.x, fmaf(w10, v10.x, w11 * v11.x)));
                    sa.y = fmaf(w00, v00.y, fmaf(w01, v01.y, fmaf(w10, v10.y, w11 * v11.y)));
                    sa.z = fmaf(w00, v00.z, fmaf(w01, v01.z, fmaf(w10, v10.z, w11 * v11.z)));
                    sa.w = fmaf(w00, v00.w, fmaf(w01, v01.w, fmaf(w10, v10.w, w11 * v11.w)));
                    const float* __restrict__ wc = wk + (c4 * 4) * COUT;
#pragma unroll
                    for (int o = 0; o < COUT; ++o) acc[o] = fmaf(wc[o], sa.x, acc[o]);
#pragma unroll
                    for (int o = 0; o < COUT; ++o) acc[o] = fmaf(wc[COUT + o], sa.y, acc[o]);
#pragma unroll
                    for (int o = 0; o < COUT; ++o) acc[o] = fmaf(wc[2 * COUT + o], sa.z, acc[o]);
#pragma unroll
                    for (int o = 0; o < COUT; ++o) acc[o] = fmaf(wc[3 * COUT + o], sa.w, acc[o]);
                }
            } else {
#pragma unroll
                for (int c = 0; c < CIN; ++c) {
                    float sa = fmaf(w00, r00[c], fmaf(w01, r01[c],
                               fmaf(w10, r10[c], w11 * r11[c])));
#pragma unroll
                    for (int o = 0; o < COUT; ++o)
                        acc[o] = fmaf(wk[c * COUT + o], sa, acc[o]);
                }
            }
        }

        if (g > 0 && active) {
#pragma unroll
            for (int o = 0; o < COUT; ++o)
                part[(g - 1) * (P * PSTR) + p * PSTR + o] = acc[o];
        }
    }

    if constexpr (KSEG > 1) __syncthreads();

    if (g == 0 && active) {
        if constexpr (KSEG > 1) {
#pragma unroll
            for (int gg = 1; gg < KSEG; ++gg)
#pragma unroll
                for (int o = 0; o < COUT; ++o)
                    acc[o] += part[(gg - 1) * (P * PSTR) + p * PSTR + o];
        }
        float* yb = y + (SPLITOUT ? (size_t)h * pstride : 0) + (size_t)b * COUT * P;
#pragma unroll
        for (int o = 0; o < COUT; ++o)
            yb[o * P + p] = SPLITOUT ? acc[o] : fmaxf(acc[o], 0.f);
    }
}

// ---------------------------------------------------------------------------
// Fused head: perm gather + FC(676->256) + ReLU + FC(256->10).
// ---------------------------------------------------------------------------
__global__ __launch_bounds__(256)
void fc_head(const float* __restrict__ x6, const float* __restrict__ w7,
             const float* __restrict__ b7, const float* __restrict__ w8,
             const float* __restrict__ b8, const int* __restrict__ perm,
             float* __restrict__ out)
{
    constexpr int BPB = 4;
    constexpr int F   = 676;
    __shared__ float sx[BPB][F];
    __shared__ float sh[BPB][256];

    const int tid = threadIdx.x;
    const int b0  = blockIdx.x * BPB;

    for (int i = tid; i < BPB * F; i += 256) {
        int bb = i / F, f = i - bb * F;
        int c = f / 169, p = f - c * 169;
        sx[bb][f] = x6[(size_t)(b0 + bb) * F + c * 169 + perm[p]];
    }
    __syncthreads();

    float acc[BPB];
#pragma unroll
    for (int bb = 0; bb < BPB; ++bb) acc[bb] = b7[tid];
#pragma unroll 4
    for (int i = 0; i < F; ++i) {
        const float wv = w7[i * 256 + tid];
#pragma unroll
        for (int bb = 0; bb < BPB; ++bb)
            acc[bb] = fmaf(sx[bb][i], wv, acc[bb]);
    }
#pragma unroll
    for (int bb = 0; bb < BPB; ++bb) sh[bb][tid] = fmaxf(acc[bb], 0.f);
    __syncthreads();

    if (tid < BPB * 10) {
        int bb = tid / 10, t = tid - bb * 10;
        float a = b8[t];
#pragma unroll 8
        for (int j = 0; j < 256; ++j)
            a = fmaf(sh[bb][j], w8[j * 10 + t], a);
        out[(size_t)(b0 + bb) * 10 + t] = a;
    }
}

// ---------------------------------------------------------------------------
extern "C" void kernel_launch(void* const* d_in, const int* in_sizes, int n_in,
                              void* d_out, int out_size, void* d_ws, size_t ws_size,
                              hipStream_t stream)
{
    const float* x    = (const float*)d_in[0];
    const float* off1 = (const float*)d_in[1];
    const float* w1   = (const float*)d_in[2];
    const float* b1   = (const float*)d_in[3];
    const float* off2 = (const float*)d_in[4];
    const float* w2   = (const float*)d_in[5];
    const float* b2   = (const float*)d_in[6];
    const float* off3 = (const float*)d_in[7];
    const float* w3   = (const float*)d_in[8];
    const float* b3   = (const float*)d_in[9];
    const float* off4 = (const float*)d_in[10];
    const float* w4   = (const float*)d_in[11];
    const float* b4   = (const float*)d_in[12];
    const float* off5 = (const float*)d_in[13];
    const float* w5   = (const float*)d_in[14];
    const float* b5   = (const float*)d_in[15];
    const float* off6 = (const float*)d_in[16];
    const float* w6   = (const float*)d_in[17];
    const float* b6   = (const float*)d_in[18];
    const float* w7   = (const float*)d_in[19];
    const float* b7   = (const float*)d_in[20];
    const float* w8   = (const float*)d_in[21];
    const float* b8   = (const float*)d_in[22];
    const int*   perm = (const int*)d_in[23];
    float* out = (float*)d_out;

    // ws layout (floats):
    //   wt   @ 0          (33,792)
    //   buf0 @ 33,792     (3,936,256)   a1 / a3(p0L3) / a5
    //   buf1 @ 3,970,048  (6,889,472)   a2 / a4-partials / a6
    //   p1L3 @ 10,859,520 (2,560,000)   [only if ws_size allows]
    const int woff[6] = {0, 144, 4752, 17552, 30096, 33296};
    float* ws   = (float*)d_ws;
    float* wt   = ws;
    float* buf0 = ws + 33792;
    float* buf1 = buf0 + 3936256;

    float* a1   = buf0;                       // 256*16*961
    float* a2   = buf1;                       // 256*32*841
    float* a3   = buf0;                       // 256*16*625 (p0 of L3 if split)
    float* p1L3 = ws + 10859520;              // 256*16*625 (gated)
    float* a4p0 = buf1;                       // 256*16*361 (L4 half-0 partial)
    float* a4p1 = buf1 + 1478656;             // 256*16*361 (L4 half-1 partial)
    float* a5   = buf0;                       // 256*8*225
    float* a6   = buf1;                       // 256*4*169

    const bool splitL3 = (ws_size >= (size_t)(10859520 + 2560000) * sizeof(float));
    const size_t pstrL3 = (size_t)(p1L3 - a3);
    const size_t pstrL4 = 1478656;

    WtArgs wa;
    wa.src[0] = w1; wa.src[1] = w2; wa.src[2] = w3;
    wa.src[3] = w4; wa.src[4] = w5; wa.src[5] = w6;
    const int cos[6] = {16, 32, 16, 16, 8, 4};
    const int cis[6] = {1, 16, 32, 16, 16, 8};
    const int k2s[6] = {9, 9, 25, 49, 25, 9};
    for (int i = 0; i < 6; ++i) {
        wa.co[i] = cos[i]; wa.ci[i] = cis[i];
        wa.k2[i] = k2s[i]; wa.dstoff[i] = woff[i];
    }
    transpose_weights<<<dim3(6), dim3(256), 0, stream>>>(wa, wt);

    const dim3 g1(256), g2(256, 2);
    // <CIN,CINW,COUT,K,H,W,HO,WO,S,KSEG,NT,COMB,SPLITOUT>
    deform_lds< 1,  1, 16, 3, 33, 33, 31, 31,  1, 1, 1024, false, false>
        <<<g1, dim3(1024), 0, stream>>>(x,  nullptr, off1, wt + woff[0], b1, a1, 0);
    deform_lds<16, 16, 32, 3, 31, 31, 29, 29, 20, 1, 1024, false, false>
        <<<g1, dim3(1024), 0, stream>>>(a1, nullptr, off2, wt + woff[1], b2, a2, 0);

    if (splitL3) {
        // L3 split: two half-channel blocks per image (67 KB LDS -> 2 blocks/CU)
        deform_lds<16, 32, 16, 5, 29, 29, 25, 25, 20, 1, 1024, false, true>
            <<<g2, dim3(1024), 0, stream>>>(a2, nullptr, off3, wt + woff[2], b3, a3, pstrL3);
        // L4 split, consuming combined L3 partials
        deform_lds< 8, 16, 16, 7, 25, 25, 19, 19, 12, 2,  768, true,  true>
            <<<g2, dim3(768),  0, stream>>>(a3, p1L3,   off4, wt + woff[3], b4, a4p0, pstrL4);
    } else {
        deform_lds<32, 32, 16, 5, 29, 29, 25, 25, 36, 1, 1024, false, false>
            <<<g1, dim3(1024), 0, stream>>>(a2, nullptr, off3, wt + woff[2], b3, a3, 0);
        deform_lds< 8, 16, 16, 7, 25, 25, 19, 19, 12, 2,  768, false, true>
            <<<g2, dim3(768),  0, stream>>>(a3, nullptr, off4, wt + woff[3], b4, a4p0, pstrL4);
    }

    // L5 consumes combined L4 partials (always split producer)
    deform_lds<16, 16,  8, 5, 19, 19, 15, 15, 20, 4, 1024, true,  false>
        <<<g1, dim3(1024), 0, stream>>>(a4p0, a4p1, off5, wt + woff[4], b5, a5, 0);
    deform_lds< 8,  8,  4, 3, 15, 15, 13, 13, 12, 5,  960, false, false>
        <<<g1, dim3(960),  0, stream>>>(a5, nullptr, off6, wt + woff[5], b6, a6, 0);

    fc_head<<<dim3(64), dim3(256), 0, stream>>>(a6, w7, b7, w8, b8, perm, out);
}

// Round 10
// 272.059 us; speedup vs baseline: 1.8988x; 1.0284x over previous
//
#include <hip/hip_runtime.h>

// ---------------------------------------------------------------------------
// Weight transpose: w[o][c][k] -> wT[(k*ci + c)*co + o]  (o contiguous so the
// compute kernel's uniform weight reads merge into s_load_dwordx4/x8).
// ---------------------------------------------------------------------------
struct WtArgs { const float* src[6]; int co[6], ci[6], k2[6], dstoff[6]; };

__global__ __launch_bounds__(256)
void transpose_weights(WtArgs a, float* __restrict__ dst0)
{
    const int L = blockIdx.x;
    const float* __restrict__ s = a.src[L];
    float* __restrict__ d = dst0 + a.dstoff[L];
    const int co = a.co[L], ci = a.ci[L], k2 = a.k2[L];
    const int n = co * ci * k2;
    for (int i = threadIdx.x; i < n; i += 256) {
        int k = i % k2;
        int c = (i / k2) % ci;
        int o = i / (k2 * ci);
        d[(k * ci + c) * co + o] = s[i];
    }
}

// ---------------------------------------------------------------------------
// Proven deformable conv kernel (round-6 core + round-9 split/comb flags):
//  NCOMB:    1 = stage x0[i] directly; 2 = stage relu(x0[i]+x1[i]) (combine a
//            split producer's partial sums on the fly).
//  SPLITOUT: grid (B, 2); blockIdx.y = h selects channels [h*CIN..h*CIN+CIN)
//            of a CINW-channel input; bias added only for h==0; stores RAW
//            partial sums (no relu) to y + h*pstride.
// x layout: [B][CINW][H*W]   y: [B][COUT][HO*WO] (per half-buffer if split)
// ---------------------------------------------------------------------------
template<int CIN, int CINW, int COUT, int K, int H, int W, int HO, int WO,
         int S, int KSEG, int NT, int NCOMB, bool SPLITOUT>
__global__ __launch_bounds__(NT)
void deform_lds(const float* __restrict__ x0, const float* __restrict__ x1,
                const float* __restrict__ off, const float* __restrict__ wT,
                const float* __restrict__ bias, float* __restrict__ y,
                size_t pstride)
{
    constexpr int K2 = K * K, HW = H * W, P = HO * WO;
    constexpr int PW = ((P + 63) / 64) * 64;
    constexpr int KLEN = (K2 + KSEG - 1) / KSEG;
    constexpr int PSTR = (COUT % 2 == 0) ? COUT + 1 : COUT;
    static_assert(NT >= KSEG * PW, "NT too small for KSEG*PW");

    __shared__ __align__(16) float simg[HW * S];
    __shared__ float part[(KSEG > 1) ? (KSEG - 1) * P * PSTR : 1];

    const int tid = threadIdx.x;
    const int b   = blockIdx.x;
    const int h   = SPLITOUT ? blockIdx.y : 0;

    // ---- stage image (channel-inner, padded stride S) ----
    const size_t xoff = (size_t)b * CINW * HW + (SPLITOUT ? (size_t)h * CIN * HW : 0);
    const float* xb  = x0 + xoff;
    const float* xb1 = (NCOMB == 2) ? (x1 + xoff) : nullptr;
    for (int i = tid; i < CIN * HW; i += NT) {
        int c = i / HW, hw = i - c * HW;
        float v;
        if constexpr (NCOMB == 2) v = fmaxf(xb[i] + xb1[i], 0.f);
        else                      v = xb[i];
        simg[hw * S + c] = v;
    }
    __syncthreads();

    const int g  = tid / PW;
    const int p  = tid - g * PW;
    const int pc = (p < P) ? p : (P - 1);
    const bool active = (p < P);

    float acc[COUT];
#pragma unroll
    for (int o = 0; o < COUT; ++o) acc[o] = 0.f;

    if (g < KSEG) {
        if (g == 0 && (!SPLITOUT || h == 0)) {
#pragma unroll
            for (int o = 0; o < COUT; ++o) acc[o] = bias[o];
        }
        const int ho = pc / WO, wo = pc - ho * WO;
        const int kb = g * KLEN;

        const int kf = (kb < K2) ? kb : (K2 - 1);
        float ndy = off[(2 * kf)     * P + pc];
        float ndx = off[(2 * kf + 1) * P + pc];

#pragma unroll 1
        for (int j = 0; j < KLEN; ++j) {
            const int k  = kb + j;
            const int kk = (k < K2) ? k : (K2 - 1);
            const float dy = ndy, dx = ndx;
            const int kn = (k + 1 < K2) ? (k + 1) : (K2 - 1);
            ndy = off[(2 * kn)     * P + pc];
            ndx = off[(2 * kn + 1) * P + pc];

            const int ky = kk / K, kx = kk - ky * K;
            const float py = (float)(ho + ky) + dy;
            const float px = (float)(wo + kx) + dx;
            const float y0f = floorf(py), x0f = floorf(px);
            const float wy = py - y0f, wx = px - x0f;
            const int y0 = (int)y0f, x0 = (int)x0f;
            const int y1 = y0 + 1,  x1i = x0 + 1;
            const bool vy0 = ((unsigned)y0  < (unsigned)H);
            const bool vy1 = ((unsigned)y1  < (unsigned)H);
            const bool vx0 = ((unsigned)x0  < (unsigned)W);
            const bool vx1 = ((unsigned)x1i < (unsigned)W);
            const int cy0 = min(max(y0, 0), H - 1) * W;
            const int cy1 = min(max(y1, 0), H - 1) * W;
            const int cx0 = min(max(x0, 0), W - 1);
            const int cx1 = min(max(x1i, 0), W - 1);
            float w00 = (vy0 && vx0) ? (1.f - wy) * (1.f - wx) : 0.f;
            float w01 = (vy0 && vx1) ? (1.f - wy) * wx         : 0.f;
            float w10 = (vy1 && vx0) ? wy * (1.f - wx)         : 0.f;
            float w11 = (vy1 && vx1) ? wy * wx                 : 0.f;
            if constexpr (K2 % KSEG != 0) {
                const float kv = (k < K2) ? 1.f : 0.f;
                w00 *= kv; w01 *= kv; w10 *= kv; w11 *= kv;
            }

            const float* __restrict__ r00 = simg + (cy0 + cx0) * S;
            const float* __restrict__ r01 = simg + (cy0 + cx1) * S;
            const float* __restrict__ r10 = simg + (cy1 + cx0) * S;
            const float* __restrict__ r11 = simg + (cy1 + cx1) * S;
            const int kku = __builtin_amdgcn_readfirstlane(kk);
            const float* __restrict__ wk = wT + kku * (CINW * COUT)
                                         + (SPLITOUT ? h * (CIN * COUT) : 0);

            if constexpr (CIN % 4 == 0) {
#pragma unroll
                for (int c4 = 0; c4 < CIN / 4; ++c4) {
                    const float4 v00 = *(const float4*)(r00 + c4 * 4);
                    const float4 v01 = *(const float4*)(r01 + c4 * 4);
                    const float4 v10 = *(const float4*)(r10 + c4 * 4);
                    const float4 v11 = *(const float4*)(r11 + c4 * 4);
                    float4 sa;
                    sa.x = fmaf(w00, v00.x, fmaf(w01, v01.x, fmaf(w10, v10.x, w11 * v11.x)));
                    sa.y = fmaf(w00, v00.y, fmaf(w01, v01.y, fmaf(w10, v10.y, w11 * v11.y)));
                    sa.z = fmaf(w00, v00.z, fmaf(w01, v01.z, fmaf(w10, v10.z, w11 * v11.z)));
                    sa.w = fmaf(w00, v00.w, fmaf(w01, v01.w, fmaf(w10, v10.w, w11 * v11.w)));
                    const float* __restrict__ wc = wk + (c4 * 4) * COUT;
#pragma unroll
                    for (int o = 0; o < COUT; ++o) acc[o] = fmaf(wc[o], sa.x, acc[o]);
#pragma unroll
                    for (int o = 0; o < COUT; ++o) acc[o] = fmaf(wc[COUT + o], sa.y, acc[o]);
#pragma unroll
                    for (int o = 0; o < COUT; ++o) acc[o] = fmaf(wc[2 * COUT + o], sa.z, acc[o]);
#pragma unroll
                    for (int o = 0; o < COUT; ++o) acc[o] = fmaf(wc[3 * COUT + o], sa.w, acc[o]);
                }
            } else {
#pragma unroll
                for (int c = 0; c < CIN; ++c) {
                    float sa = fmaf(w00, r00[c], fmaf(w01, r01[c],
                               fmaf(w10, r10[c], w11 * r11[c])));
#pragma unroll
                    for (int o = 0; o < COUT; ++o)
                        acc[o] = fmaf(wk[c * COUT + o], sa, acc[o]);
                }
            }
        }

        if (g > 0 && active) {
#pragma unroll
            for (int o = 0; o < COUT; ++o)
                part[(g - 1) * (P * PSTR) + p * PSTR + o] = acc[o];
        }
    }

    if constexpr (KSEG > 1) __syncthreads();

    if (g == 0 && active) {
        if constexpr (KSEG > 1) {
#pragma unroll
            for (int gg = 1; gg < KSEG; ++gg)
#pragma unroll
                for (int o = 0; o < COUT; ++o)
                    acc[o] += part[(gg - 1) * (P * PSTR) + p * PSTR + o];
        }
        float* yb = y + (SPLITOUT ? (size_t)h * pstride : 0) + (size_t)b * COUT * P;
#pragma unroll
        for (int o = 0; o < COUT; ++o)
            yb[o * P + p] = SPLITOUT ? acc[o] : fmaxf(acc[o], 0.f);
    }
}

// ---------------------------------------------------------------------------
// Fused head: perm gather + FC(676->256) + ReLU + FC(256->10).
// 256 blocks x 256 threads; one batch row per block (1 block/CU).
// ---------------------------------------------------------------------------
__global__ __launch_bounds__(256)
void fc_head(const float* __restrict__ x6, const float* __restrict__ w7,
             const float* __restrict__ b7, const float* __restrict__ w8,
             const float* __restrict__ b8, const int* __restrict__ perm,
             float* __restrict__ out)
{
    constexpr int F = 676;
    __shared__ float sx[F];
    __shared__ float sh[256];

    const int tid = threadIdx.x;
    const int b   = blockIdx.x;

    for (int i = tid; i < F; i += 256) {
        int c = i / 169, p = i - c * 169;
        sx[i] = x6[(size_t)b * F + c * 169 + perm[p]];
    }
    __syncthreads();

    float acc = b7[tid];
#pragma unroll 4
    for (int i = 0; i < F; ++i)
        acc = fmaf(sx[i], w7[i * 256 + tid], acc);   // sx broadcast, w7 coalesced
    sh[tid] = fmaxf(acc, 0.f);
    __syncthreads();

    if (tid < 10) {
        float a = b8[tid];
#pragma unroll 8
        for (int j = 0; j < 256; ++j)
            a = fmaf(sh[j], w8[j * 10 + tid], a);
        out[(size_t)b * 10 + tid] = a;
    }
}

// ---------------------------------------------------------------------------
extern "C" void kernel_launch(void* const* d_in, const int* in_sizes, int n_in,
                              void* d_out, int out_size, void* d_ws, size_t ws_size,
                              hipStream_t stream)
{
    const float* x    = (const float*)d_in[0];
    const float* off1 = (const float*)d_in[1];
    const float* w1   = (const float*)d_in[2];
    const float* b1   = (const float*)d_in[3];
    const float* off2 = (const float*)d_in[4];
    const float* w2   = (const float*)d_in[5];
    const float* b2   = (const float*)d_in[6];
    const float* off3 = (const float*)d_in[7];
    const float* w3   = (const float*)d_in[8];
    const float* b3   = (const float*)d_in[9];
    const float* off4 = (const float*)d_in[10];
    const float* w4   = (const float*)d_in[11];
    const float* b4   = (const float*)d_in[12];
    const float* off5 = (const float*)d_in[13];
    const float* w5   = (const float*)d_in[14];
    const float* b5   = (const float*)d_in[15];
    const float* off6 = (const float*)d_in[16];
    const float* w6   = (const float*)d_in[17];
    const float* b6   = (const float*)d_in[18];
    const float* w7   = (const float*)d_in[19];
    const float* b7   = (const float*)d_in[20];
    const float* w8   = (const float*)d_in[21];
    const float* b8   = (const float*)d_in[22];
    const int*   perm = (const int*)d_in[23];
    float* out = (float*)d_out;

    // ws layout (floats):
    //   wt   @ 0           (33,792)
    //   buf0 @ 33,792      (3,936,256)   a1 / a3(p0L3) / a5
    //   buf1 @ 3,970,048   (6,889,472)   a2(p0L2) / a4-partials / a6
    //   p1L3 @ 10,859,520  (2,560,000)   [gate: splitL3]
    //   p1L2 @ 13,419,520  (6,889,472)   [gate: splitL2]
    const int woff[6] = {0, 144, 4752, 17552, 30096, 33296};
    float* ws   = (float*)d_ws;
    float* wt   = ws;
    float* buf0 = ws + 33792;
    float* buf1 = buf0 + 3936256;

    float* a1   = buf0;                       // 256*16*961
    float* a2   = buf1;                       // 256*32*841 (p0 of L2 if split)
    float* p1L2 = ws + 13419520;              // 256*32*841 (gated)
    float* a3   = buf0;                       // 256*16*625 (p0 of L3 if split)
    float* p1L3 = ws + 10859520;              // 256*16*625 (gated)
    float* a4p0 = buf1;                       // 256*16*361 (L4 half-0 partial)
    float* a4p1 = buf1 + 1478656;             // 256*16*361 (L4 half-1 partial)
    float* a5   = buf0;                       // 256*8*225
    float* a6   = buf1;                       // 256*4*169

    const bool splitL3 = (ws_size >= (size_t)13419520 * sizeof(float));
    const bool splitL2 = (ws_size >= (size_t)20308992 * sizeof(float));
    const size_t pstrL3 = (size_t)(p1L3 - a3);
    const size_t pstrL2 = (size_t)(p1L2 - a2);
    const size_t pstrL4 = 1478656;

    WtArgs wa;
    wa.src[0] = w1; wa.src[1] = w2; wa.src[2] = w3;
    wa.src[3] = w4; wa.src[4] = w5; wa.src[5] = w6;
    const int cos[6] = {16, 32, 16, 16, 8, 4};
    const int cis[6] = {1, 16, 32, 16, 16, 8};
    const int k2s[6] = {9, 9, 25, 49, 25, 9};
    for (int i = 0; i < 6; ++i) {
        wa.co[i] = cos[i]; wa.ci[i] = cis[i];
        wa.k2[i] = k2s[i]; wa.dstoff[i] = woff[i];
    }
    transpose_weights<<<dim3(6), dim3(256), 0, stream>>>(wa, wt);

    const dim3 g1(256), g2(256, 2);
    // <CIN,CINW,COUT,K,H,W,HO,WO,S,KSEG,NT,NCOMB,SPLITOUT>
    deform_lds< 1,  1, 16, 3, 33, 33, 31, 31,  1, 1, 1024, 1, false>
        <<<g1, dim3(1024), 0, stream>>>(x,  nullptr, off1, wt + woff[0], b1, a1, 0);

    if (splitL2) {
        // L2 split: halves CIN=8, 46.1 KB LDS -> 2 blocks/CU, 28 active waves
        deform_lds< 8, 16, 32, 3, 31, 31, 29, 29, 12, 1, 1024, 1, true>
            <<<g2, dim3(1024), 0, stream>>>(a1, nullptr, off2, wt + woff[1], b2, a2, pstrL2);
    } else {
        deform_lds<16, 16, 32, 3, 31, 31, 29, 29, 20, 1, 1024, 1, false>
            <<<g1, dim3(1024), 0, stream>>>(a1, nullptr, off2, wt + woff[1], b2, a2, 0);
    }

    if (splitL3) {
        if (splitL2) {
            deform_lds<16, 32, 16, 5, 29, 29, 25, 25, 20, 1, 1024, 2, true>
                <<<g2, dim3(1024), 0, stream>>>(a2, p1L2, off3, wt + woff[2], b3, a3, pstrL3);
        } else {
            deform_lds<16, 32, 16, 5, 29, 29, 25, 25, 20, 1, 1024, 1, true>
                <<<g2, dim3(1024), 0, stream>>>(a2, nullptr, off3, wt + woff[2], b3, a3, pstrL3);
        }
        deform_lds< 8, 16, 16, 7, 25, 25, 19, 19, 12, 2,  768, 2, true>
            <<<g2, dim3(768),  0, stream>>>(a3, p1L3, off4, wt + woff[3], b4, a4p0, pstrL4);
    } else {
        deform_lds<32, 32, 16, 5, 29, 29, 25, 25, 36, 1, 1024, 1, false>
            <<<g1, dim3(1024), 0, stream>>>(a2, nullptr, off3, wt + woff[2], b3, a3, 0);
        deform_lds< 8, 16, 16, 7, 25, 25, 19, 19, 12, 2,  768, 1, true>
            <<<g2, dim3(768),  0, stream>>>(a3, nullptr, off4, wt + woff[3], b4, a4p0, pstrL4);
    }

    // L5 consumes combined L4 partials (always split producer)
    deform_lds<16, 16,  8, 5, 19, 19, 15, 15, 20, 4, 1024, 2, false>
        <<<g1, dim3(1024), 0, stream>>>(a4p0, a4p1, off5, wt + woff[4], b5, a5, 0);
    deform_lds< 8,  8,  4, 3, 15, 15, 13, 13, 12, 5,  960, 1, false>
        <<<g1, dim3(960),  0, stream>>>(a5, nullptr, off6, wt + woff[5], b6, a6, 0);

    fc_head<<<dim3(256), dim3(256), 0, stream>>>(a6, w7, b7, w8, b8, perm, out);
}

// Round 11
// 270.987 us; speedup vs baseline: 1.9063x; 1.0040x over previous
//
#include <hip/hip_runtime.h>

// ---------------------------------------------------------------------------
// Weight transpose: w[o][c][k] -> wT[(k*ci + c)*co + o].
// ---------------------------------------------------------------------------
struct WtArgs { const float* src[6]; int co[6], ci[6], k2[6], dstoff[6]; };

__global__ __launch_bounds__(256)
void transpose_weights(WtArgs a, float* __restrict__ dst0)
{
    const int L = blockIdx.x;
    const float* __restrict__ s = a.src[L];
    float* __restrict__ d = dst0 + a.dstoff[L];
    const int co = a.co[L], ci = a.ci[L], k2 = a.k2[L];
    const int n = co * ci * k2;
    for (int i = threadIdx.x; i < n; i += 256) {
        int k = i % k2;
        int c = (i / k2) % ci;
        int o = i / (k2 * ci);
        d[(k * ci + c) * co + o] = s[i];
    }
}

// ---------------------------------------------------------------------------
// Batch-invariant bilinear metadata tables: for each layer, entry e = k*P+p
// holds {int4 corner-pixel-indices, float4 corner-weights} (32 B). Offsets
// are shared across the batch, so this is computed ONCE instead of 256x.
// ---------------------------------------------------------------------------
struct MetaArgs { const float* off[6]; int P[6], K[6], WO[6], H[6], W[6], base[6]; };

__global__ __launch_bounds__(256)
void build_meta(MetaArgs a, float* __restrict__ meta0)
{
    const int L = blockIdx.y;
    const float* __restrict__ off = a.off[L];
    const int P = a.P[L], K = a.K[L], WOv = a.WO[L], H = a.H[L], Wv = a.W[L];
    const int N = P * K * K;
    float* __restrict__ m = meta0 + (size_t)a.base[L] * 8;
    for (int e = blockIdx.x * 256 + threadIdx.x; e < N; e += gridDim.x * 256) {
        const int k = e / P, p = e - k * P;
        const int ho = p / WOv, wo = p - ho * WOv;
        const int ky = k / K, kx = k - ky * K;
        const float dy = off[(2 * k)     * P + p];
        const float dx = off[(2 * k + 1) * P + p];
        const float py = (float)(ho + ky) + dy;
        const float px = (float)(wo + kx) + dx;
        const float y0f = floorf(py), x0f = floorf(px);
        const float wy = py - y0f, wx = px - x0f;
        const int y0 = (int)y0f, x0 = (int)x0f;
        const int y1 = y0 + 1,  x1 = x0 + 1;
        const bool vy0 = ((unsigned)y0 < (unsigned)H);
        const bool vy1 = ((unsigned)y1 < (unsigned)H);
        const bool vx0 = ((unsigned)x0 < (unsigned)Wv);
        const bool vx1 = ((unsigned)x1 < (unsigned)Wv);
        const int cy0 = min(max(y0, 0), H - 1) * Wv;
        const int cy1 = min(max(y1, 0), H - 1) * Wv;
        const int cx0 = min(max(x0, 0), Wv - 1);
        const int cx1 = min(max(x1, 0), Wv - 1);
        int4 mi;
        mi.x = cy0 + cx0; mi.y = cy0 + cx1; mi.z = cy1 + cx0; mi.w = cy1 + cx1;
        float4 mw;
        mw.x = (vy0 && vx0) ? (1.f - wy) * (1.f - wx) : 0.f;
        mw.y = (vy0 && vx1) ? (1.f - wy) * wx         : 0.f;
        mw.z = (vy1 && vx0) ? wy * (1.f - wx)         : 0.f;
        mw.w = (vy1 && vx1) ? wy * wx                 : 0.f;
        *(int4*)(m + (size_t)e * 8)     = mi;
        *(float4*)(m + (size_t)e * 8 + 4) = mw;
    }
}

// ---------------------------------------------------------------------------
// Proven deformable conv kernel (round-6 core + split/comb flags) + MET:
//  MET=true : sampling metadata from precomputed table (2x b128 loads/(p,k))
//  MET=false: inline metadata computation (round-10 behavior, fallback)
//  NCOMB=2  : staging reads relu(x0[i]+x1[i]) (combine split partials)
//  SPLITOUT : grid (B,2); h = channel-half; raw partial sums to y+h*pstride
// ---------------------------------------------------------------------------
template<int CIN, int CINW, int COUT, int K, int H, int W, int HO, int WO,
         int S, int KSEG, int NT, int NCOMB, bool SPLITOUT, bool MET>
__global__ __launch_bounds__(NT)
void deform_lds(const float* __restrict__ x0, const float* __restrict__ x1,
                const float* __restrict__ off, const float* __restrict__ meta,
                const float* __restrict__ wT, const float* __restrict__ bias,
                float* __restrict__ y, size_t pstride)
{
    constexpr int K2 = K * K, HW = H * W, P = HO * WO;
    constexpr int PW = ((P + 63) / 64) * 64;
    constexpr int KLEN = (K2 + KSEG - 1) / KSEG;
    constexpr int PSTR = (COUT % 2 == 0) ? COUT + 1 : COUT;
    static_assert(NT >= KSEG * PW, "NT too small for KSEG*PW");

    __shared__ __align__(16) float simg[HW * S];
    __shared__ float part[(KSEG > 1) ? (KSEG - 1) * P * PSTR : 1];

    const int tid = threadIdx.x;
    const int b   = blockIdx.x;
    const int h   = SPLITOUT ? blockIdx.y : 0;

    // ---- stage image (channel-inner, padded stride S) ----
    const size_t xoff = (size_t)b * CINW * HW + (SPLITOUT ? (size_t)h * CIN * HW : 0);
    const float* xb  = x0 + xoff;
    const float* xb1 = (NCOMB == 2) ? (x1 + xoff) : nullptr;
    for (int i = tid; i < CIN * HW; i += NT) {
        int c = i / HW, hw = i - c * HW;
        float v;
        if constexpr (NCOMB == 2) v = fmaxf(xb[i] + xb1[i], 0.f);
        else                      v = xb[i];
        simg[hw * S + c] = v;
    }
    __syncthreads();

    const int g  = tid / PW;
    const int p  = tid - g * PW;
    const int pc = (p < P) ? p : (P - 1);
    const bool active = (p < P);

    float acc[COUT];
#pragma unroll
    for (int o = 0; o < COUT; ++o) acc[o] = 0.f;

    if (g < KSEG) {
        if (g == 0 && (!SPLITOUT || h == 0)) {
#pragma unroll
            for (int o = 0; o < COUT; ++o) acc[o] = bias[o];
        }
        const int ho = pc / WO, wo = pc - ho * WO;
        const int kb = g * KLEN;

        // FMA core shared by both meta paths
        auto fma_block = [&](int i00, int i01, int i10, int i11,
                             float w00, float w01, float w10, float w11,
                             int kku) {
            const float* __restrict__ r00 = simg + i00 * S;
            const float* __restrict__ r01 = simg + i01 * S;
            const float* __restrict__ r10 = simg + i10 * S;
            const float* __restrict__ r11 = simg + i11 * S;
            const float* __restrict__ wk = wT + kku * (CINW * COUT)
                                         + (SPLITOUT ? h * (CIN * COUT) : 0);
            if constexpr (CIN % 4 == 0) {
#pragma unroll
                for (int c4 = 0; c4 < CIN / 4; ++c4) {
                    const float4 v00 = *(const float4*)(r00 + c4 * 4);
                    const float4 v01 = *(const float4*)(r01 + c4 * 4);
                    const float4 v10 = *(const float4*)(r10 + c4 * 4);
                    const float4 v11 = *(const float4*)(r11 + c4 * 4);
                    float4 sa;
                    sa.x = fmaf(w00, v00.x, fmaf(w01, v01.x, fmaf(w10, v10.x, w11 * v11.x)));
                    sa.y = fmaf(w00, v00.y, fmaf(w01, v01.y, fmaf(w10, v10.y, w11 * v11.y)));
                    sa.z = fmaf(w00, v00.z, fmaf(w01, v01.z, fmaf(w10, v10.z, w11 * v11.z)));
                    sa.w = fmaf(w00, v00.w, fmaf(w01, v01.w, fmaf(w10, v10.w, w11 * v11.w)));
                    const float* __restrict__ wc = wk + (c4 * 4) * COUT;
#pragma unroll
                    for (int o = 0; o < COUT; ++o) acc[o] = fmaf(wc[o], sa.x, acc[o]);
#pragma unroll
                    for (int o = 0; o < COUT; ++o) acc[o] = fmaf(wc[COUT + o], sa.y, acc[o]);
#pragma unroll
                    for (int o = 0; o < COUT; ++o) acc[o] = fmaf(wc[2 * COUT + o], sa.z, acc[o]);
#pragma unroll
                    for (int o = 0; o < COUT; ++o) acc[o] = fmaf(wc[3 * COUT + o], sa.w, acc[o]);
                }
            } else {
#pragma unroll
                for (int c = 0; c < CIN; ++c) {
                    float sa = fmaf(w00, r00[c], fmaf(w01, r01[c],
                               fmaf(w10, r10[c], w11 * r11[c])));
#pragma unroll
                    for (int o = 0; o < COUT; ++o)
                        acc[o] = fmaf(wk[c * COUT + o], sa, acc[o]);
                }
            }
        };

        if constexpr (MET) {
            // prefetched metadata (distance 1)
            const int kf = (kb < K2) ? kb : (K2 - 1);
            int4   nmi = *(const int4*)  (meta + (size_t)(kf * P + pc) * 8);
            float4 nmw = *(const float4*)(meta + (size_t)(kf * P + pc) * 8 + 4);

#pragma unroll 1
            for (int j = 0; j < KLEN; ++j) {
                const int k  = kb + j;
                const int kk = (k < K2) ? k : (K2 - 1);
                const int4   mi  = nmi;
                const float4 mwv = nmw;
                const int kn = (k + 1 < K2) ? (k + 1) : (K2 - 1);
                nmi = *(const int4*)  (meta + (size_t)(kn * P + pc) * 8);
                nmw = *(const float4*)(meta + (size_t)(kn * P + pc) * 8 + 4);

                float w00 = mwv.x, w01 = mwv.y, w10 = mwv.z, w11 = mwv.w;
                if constexpr (K2 % KSEG != 0) {
                    const float kv = (k < K2) ? 1.f : 0.f;
                    w00 *= kv; w01 *= kv; w10 *= kv; w11 *= kv;
                }
                const int kku = __builtin_amdgcn_readfirstlane(kk);
                fma_block(mi.x, mi.y, mi.z, mi.w, w00, w01, w10, w11, kku);
            }
        } else {
            const int kf = (kb < K2) ? kb : (K2 - 1);
            float ndy = off[(2 * kf)     * P + pc];
            float ndx = off[(2 * kf + 1) * P + pc];

#pragma unroll 1
            for (int j = 0; j < KLEN; ++j) {
                const int k  = kb + j;
                const int kk = (k < K2) ? k : (K2 - 1);
                const float dy = ndy, dx = ndx;
                const int kn = (k + 1 < K2) ? (k + 1) : (K2 - 1);
                ndy = off[(2 * kn)     * P + pc];
                ndx = off[(2 * kn + 1) * P + pc];

                const int ky = kk / K, kx = kk - ky * K;
                const float py = (float)(ho + ky) + dy;
                const float px = (float)(wo + kx) + dx;
                const float y0f = floorf(py), x0f = floorf(px);
                const float wy = py - y0f, wx = px - x0f;
                const int y0 = (int)y0f, x0 = (int)x0f;
                const int y1 = y0 + 1,  x1i = x0 + 1;
                const bool vy0 = ((unsigned)y0  < (unsigned)H);
                const bool vy1 = ((unsigned)y1  < (unsigned)H);
                const bool vx0 = ((unsigned)x0  < (unsigned)W);
                const bool vx1 = ((unsigned)x1i < (unsigned)W);
                const int cy0 = min(max(y0, 0), H - 1) * W;
                const int cy1 = min(max(y1, 0), H - 1) * W;
                const int cx0 = min(max(x0, 0), W - 1);
                const int cx1 = min(max(x1i, 0), W - 1);
                float w00 = (vy0 && vx0) ? (1.f - wy) * (1.f - wx) : 0.f;
                float w01 = (vy0 && vx1) ? (1.f - wy) * wx         : 0.f;
                float w10 = (vy1 && vx0) ? wy * (1.f - wx)         : 0.f;
                float w11 = (vy1 && vx1) ? wy * wx                 : 0.f;
                if constexpr (K2 % KSEG != 0) {
                    const float kv = (k < K2) ? 1.f : 0.f;
                    w00 *= kv; w01 *= kv; w10 *= kv; w11 *= kv;
                }
                const int kku = __builtin_amdgcn_readfirstlane(kk);
                fma_block(cy0 + cx0, cy0 + cx1, cy1 + cx0, cy1 + cx1,
                          w00, w01, w10, w11, kku);
            }
        }

        if (g > 0 && active) {
#pragma unroll
            for (int o = 0; o < COUT; ++o)
                part[(g - 1) * (P * PSTR) + p * PSTR + o] = acc[o];
        }
    }

    if constexpr (KSEG > 1) __syncthreads();

    if (g == 0 && active) {
        if constexpr (KSEG > 1) {
#pragma unroll
            for (int gg = 1; gg < KSEG; ++gg)
#pragma unroll
                for (int o = 0; o < COUT; ++o)
                    acc[o] += part[(gg - 1) * (P * PSTR) + p * PSTR + o];
        }
        float* yb = y + (SPLITOUT ? (size_t)h * pstride : 0) + (size_t)b * COUT * P;
#pragma unroll
        for (int o = 0; o < COUT; ++o)
            yb[o * P + p] = SPLITOUT ? acc[o] : fmaxf(acc[o], 0.f);
    }
}

// ---------------------------------------------------------------------------
// Fused head: perm gather + FC(676->256) + ReLU + FC(256->10).
// 256 blocks x 256 threads; one batch row per block.
// ---------------------------------------------------------------------------
__global__ __launch_bounds__(256)
void fc_head(const float* __restrict__ x6, const float* __restrict__ w7,
             const float* __restrict__ b7, const float* __restrict__ w8,
             const float* __restrict__ b8, const int* __restrict__ perm,
             float* __restrict__ out)
{
    constexpr int F = 676;
    __shared__ float sx[F];
    __shared__ float sh[256];

    const int tid = threadIdx.x;
    const int b   = blockIdx.x;

    for (int i = tid; i < F; i += 256) {
        int c = i / 169, p = i - c * 169;
        sx[i] = x6[(size_t)b * F + c * 169 + perm[p]];
    }
    __syncthreads();

    float acc = b7[tid];
#pragma unroll 4
    for (int i = 0; i < F; ++i)
        acc = fmaf(sx[i], w7[i * 256 + tid], acc);
    sh[tid] = fmaxf(acc, 0.f);
    __syncthreads();

    if (tid < 10) {
        float a = b8[tid];
#pragma unroll 8
        for (int j = 0; j < 256; ++j)
            a = fmaf(sh[j], w8[j * 10 + tid], a);
        out[(size_t)b * 10 + tid] = a;
    }
}

// ---------------------------------------------------------------------------
extern "C" void kernel_launch(void* const* d_in, const int* in_sizes, int n_in,
                              void* d_out, int out_size, void* d_ws, size_t ws_size,
                              hipStream_t stream)
{
    const float* x    = (const float*)d_in[0];
    const float* off1 = (const float*)d_in[1];
    const float* w1   = (const float*)d_in[2];
    const float* b1   = (const float*)d_in[3];
    const float* off2 = (const float*)d_in[4];
    const float* w2   = (const float*)d_in[5];
    const float* b2   = (const float*)d_in[6];
    const float* off3 = (const float*)d_in[7];
    const float* w3   = (const float*)d_in[8];
    const float* b3   = (const float*)d_in[9];
    const float* off4 = (const float*)d_in[10];
    const float* w4   = (const float*)d_in[11];
    const float* b4   = (const float*)d_in[12];
    const float* off5 = (const float*)d_in[13];
    const float* w5   = (const float*)d_in[14];
    const float* b5   = (const float*)d_in[15];
    const float* off6 = (const float*)d_in[16];
    const float* w6   = (const float*)d_in[17];
    const float* b6   = (const float*)d_in[18];
    const float* w7   = (const float*)d_in[19];
    const float* b7   = (const float*)d_in[20];
    const float* w8   = (const float*)d_in[21];
    const float* b8   = (const float*)d_in[22];
    const int*   perm = (const int*)d_in[23];
    float* out = (float*)d_out;

    // ws layout (floats):
    //   wt   @ 0           (33,792)
    //   buf0 @ 33,792      (3,936,256)   a1 / a3(p0L3) / a5
    //   buf1 @ 3,970,048   (6,889,472)   a2(p0L2) / a4-partials / a6
    //   p1L3 @ 10,859,520  (2,560,000)
    //   p1L2 @ 13,419,520  (6,889,472)
    //   meta @ 20,308,992  (453,424)     [gate: metaOK]
    const int woff[6] = {0, 144, 4752, 17552, 30096, 33296};
    float* ws   = (float*)d_ws;
    float* wt   = ws;
    float* buf0 = ws + 33792;
    float* buf1 = buf0 + 3936256;

    float* a1   = buf0;
    float* a2   = buf1;
    float* p1L2 = ws + 13419520;
    float* a3   = buf0;
    float* p1L3 = ws + 10859520;
    float* a4p0 = buf1;
    float* a4p1 = buf1 + 1478656;
    float* a5   = buf0;
    float* a6   = buf1;
    float* meta = ws + 20308992;

    // meta entry bases (entries of 8 floats): P*K2 per layer
    const int mbase[6] = {0, 8649, 16218, 31843, 49532, 55157};
    const int MTOT = 56678;

    const bool splitL3 = (ws_size >= (size_t)13419520 * sizeof(float));
    const bool splitL2 = (ws_size >= (size_t)20308992 * sizeof(float));
    const bool metaOK  = (ws_size >= (size_t)(20308992 + MTOT * 8) * sizeof(float));
    const size_t pstrL3 = (size_t)(p1L3 - a3);
    const size_t pstrL2 = (size_t)(p1L2 - a2);
    const size_t pstrL4 = 1478656;

    WtArgs wa;
    wa.src[0] = w1; wa.src[1] = w2; wa.src[2] = w3;
    wa.src[3] = w4; wa.src[4] = w5; wa.src[5] = w6;
    const int cos[6] = {16, 32, 16, 16, 8, 4};
    const int cis[6] = {1, 16, 32, 16, 16, 8};
    const int k2s[6] = {9, 9, 25, 49, 25, 9};
    for (int i = 0; i < 6; ++i) {
        wa.co[i] = cos[i]; wa.ci[i] = cis[i];
        wa.k2[i] = k2s[i]; wa.dstoff[i] = woff[i];
    }
    transpose_weights<<<dim3(6), dim3(256), 0, stream>>>(wa, wt);

    const dim3 g1(256), g2(256, 2);

    if (metaOK) {
        MetaArgs ma;
        ma.off[0] = off1; ma.off[1] = off2; ma.off[2] = off3;
        ma.off[3] = off4; ma.off[4] = off5; ma.off[5] = off6;
        const int Ps[6]  = {961, 841, 625, 361, 225, 169};
        const int Ks[6]  = {3, 3, 5, 7, 5, 3};
        const int WOs[6] = {31, 29, 25, 19, 15, 13};
        const int Hs[6]  = {33, 31, 29, 25, 19, 15};
        const int Ws_[6] = {33, 31, 29, 25, 19, 15};
        for (int i = 0; i < 6; ++i) {
            ma.P[i] = Ps[i]; ma.K[i] = Ks[i]; ma.WO[i] = WOs[i];
            ma.H[i] = Hs[i]; ma.W[i] = Ws_[i]; ma.base[i] = mbase[i];
        }
        build_meta<<<dim3(64, 6), dim3(256), 0, stream>>>(ma, meta);

        // <CIN,CINW,COUT,K,H,W,HO,WO,S,KSEG,NT,NCOMB,SPLITOUT,MET>
        deform_lds< 1,  1, 16, 3, 33, 33, 31, 31,  1, 1, 1024, 1, false, true>
            <<<g1, dim3(1024), 0, stream>>>(x, nullptr, off1, meta + (size_t)mbase[0]*8, wt + woff[0], b1, a1, 0);
        deform_lds< 8, 16, 32, 3, 31, 31, 29, 29, 12, 1,  896, 1, true,  true>
            <<<g2, dim3(896),  0, stream>>>(a1, nullptr, off2, meta + (size_t)mbase[1]*8, wt + woff[1], b2, a2, pstrL2);
        deform_lds<16, 32, 16, 5, 29, 29, 25, 25, 20, 1,  640, 2, true,  true>
            <<<g2, dim3(640),  0, stream>>>(a2, p1L2,   off3, meta + (size_t)mbase[2]*8, wt + woff[2], b3, a3, pstrL3);
        deform_lds< 8, 16, 16, 7, 25, 25, 19, 19, 12, 2,  768, 2, true,  true>
            <<<g2, dim3(768),  0, stream>>>(a3, p1L3,   off4, meta + (size_t)mbase[3]*8, wt + woff[3], b4, a4p0, pstrL4);
        deform_lds<16, 16,  8, 5, 19, 19, 15, 15, 20, 4, 1024, 2, false, true>
            <<<g1, dim3(1024), 0, stream>>>(a4p0, a4p1, off5, meta + (size_t)mbase[4]*8, wt + woff[4], b5, a5, 0);
        deform_lds< 8,  8,  4, 3, 15, 15, 13, 13, 12, 5,  960, 1, false, true>
            <<<g1, dim3(960),  0, stream>>>(a5, nullptr, off6, meta + (size_t)mbase[5]*8, wt + woff[5], b6, a6, 0);
    } else {
        // exact round-10 fallback (MET=false)
        deform_lds< 1,  1, 16, 3, 33, 33, 31, 31,  1, 1, 1024, 1, false, false>
            <<<g1, dim3(1024), 0, stream>>>(x, nullptr, off1, nullptr, wt + woff[0], b1, a1, 0);
        if (splitL2) {
            deform_lds< 8, 16, 32, 3, 31, 31, 29, 29, 12, 1, 1024, 1, true, false>
                <<<g2, dim3(1024), 0, stream>>>(a1, nullptr, off2, nullptr, wt + woff[1], b2, a2, pstrL2);
        } else {
            deform_lds<16, 16, 32, 3, 31, 31, 29, 29, 20, 1, 1024, 1, false, false>
                <<<g1, dim3(1024), 0, stream>>>(a1, nullptr, off2, nullptr, wt + woff[1], b2, a2, 0);
        }
        if (splitL3) {
            if (splitL2) {
                deform_lds<16, 32, 16, 5, 29, 29, 25, 25, 20, 1, 1024, 2, true, false>
                    <<<g2, dim3(1024), 0, stream>>>(a2, p1L2, off3, nullptr, wt + woff[2], b3, a3, pstrL3);
            } else {
                deform_lds<16, 32, 16, 5, 29, 29, 25, 25, 20, 1, 1024, 1, true, false>
                    <<<g2, dim3(1024), 0, stream>>>(a2, nullptr, off3, nullptr, wt + woff[2], b3, a3, pstrL3);
            }
            deform_lds< 8, 16, 16, 7, 25, 25, 19, 19, 12, 2,  768, 2, true, false>
                <<<g2, dim3(768),  0, stream>>>(a3, p1L3, off4, nullptr, wt + woff[3], b4, a4p0, pstrL4);
        } else {
            deform_lds<32, 32, 16, 5, 29, 29, 25, 25, 36, 1, 1024, 1, false, false>
                <<<g1, dim3(1024), 0, stream>>>(a2, nullptr, off3, nullptr, wt + woff[2], b3, a3, 0);
            deform_lds< 8, 16, 16, 7, 25, 25, 19, 19, 12, 2,  768, 1, true, false>
                <<<g2, dim3(768),  0, stream>>>(a3, nullptr, off4, nullptr, wt + woff[3], b4, a4p0, pstrL4);
        }
        deform_lds<16, 16,  8, 5, 19, 19, 15, 15, 20, 4, 1024, 2, false, false>
            <<<g1, dim3(1024), 0, stream>>>(a4p0, a4p1, off5, nullptr, wt + woff[4], b5, a5, 0);
        deform_lds< 8,  8,  4, 3, 15, 15, 13, 13, 12, 5,  960, 1, false, false>
            <<<g1, dim3(960),  0, stream>>>(a5, nullptr, off6, nullptr, wt + woff[5], b6, a6, 0);
    }

    fc_head<<<dim3(256), dim3(256), 0, stream>>>(a6, w7, b7, w8, b8, perm, out);
}

// Round 12
// 268.923 us; speedup vs baseline: 1.9210x; 1.0077x over previous
//
#include <hip/hip_runtime.h>

// ---------------------------------------------------------------------------
// Weight transpose: w[o][c][k] -> wT[(k*ci + c)*co + o].
// ---------------------------------------------------------------------------
struct WtArgs { const float* src[6]; int co[6], ci[6], k2[6], dstoff[6]; };

__global__ __launch_bounds__(256)
void transpose_weights(WtArgs a, float* __restrict__ dst0)
{
    const int L = blockIdx.x;
    const float* __restrict__ s = a.src[L];
    float* __restrict__ d = dst0 + a.dstoff[L];
    const int co = a.co[L], ci = a.ci[L], k2 = a.k2[L];
    const int n = co * ci * k2;
    for (int i = threadIdx.x; i < n; i += 256) {
        int k = i % k2;
        int c = (i / k2) % ci;
        int o = i / (k2 * ci);
        d[(k * ci + c) * co + o] = s[i];
    }
}

// ---------------------------------------------------------------------------
// Batch-invariant bilinear metadata tables: entry e = k*P+p holds
// {int4 corner-pixel-indices, float4 corner-weights} (32 B).
// ---------------------------------------------------------------------------
struct MetaArgs { const float* off[6]; int P[6], K[6], WO[6], H[6], W[6], base[6]; };

__global__ __launch_bounds__(256)
void build_meta(MetaArgs a, float* __restrict__ meta0)
{
    const int L = blockIdx.y;
    const float* __restrict__ off = a.off[L];
    const int P = a.P[L], K = a.K[L], WOv = a.WO[L], H = a.H[L], Wv = a.W[L];
    const int N = P * K * K;
    float* __restrict__ m = meta0 + (size_t)a.base[L] * 8;
    for (int e = blockIdx.x * 256 + threadIdx.x; e < N; e += gridDim.x * 256) {
        const int k = e / P, p = e - k * P;
        const int ho = p / WOv, wo = p - ho * WOv;
        const int ky = k / K, kx = k - ky * K;
        const float dy = off[(2 * k)     * P + p];
        const float dx = off[(2 * k + 1) * P + p];
        const float py = (float)(ho + ky) + dy;
        const float px = (float)(wo + kx) + dx;
        const float y0f = floorf(py), x0f = floorf(px);
        const float wy = py - y0f, wx = px - x0f;
        const int y0 = (int)y0f, x0 = (int)x0f;
        const int y1 = y0 + 1,  x1 = x0 + 1;
        const bool vy0 = ((unsigned)y0 < (unsigned)H);
        const bool vy1 = ((unsigned)y1 < (unsigned)H);
        const bool vx0 = ((unsigned)x0 < (unsigned)Wv);
        const bool vx1 = ((unsigned)x1 < (unsigned)Wv);
        const int cy0 = min(max(y0, 0), H - 1) * Wv;
        const int cy1 = min(max(y1, 0), H - 1) * Wv;
        const int cx0 = min(max(x0, 0), Wv - 1);
        const int cx1 = min(max(x1, 0), Wv - 1);
        int4 mi;
        mi.x = cy0 + cx0; mi.y = cy0 + cx1; mi.z = cy1 + cx0; mi.w = cy1 + cx1;
        float4 mw;
        mw.x = (vy0 && vx0) ? (1.f - wy) * (1.f - wx) : 0.f;
        mw.y = (vy0 && vx1) ? (1.f - wy) * wx         : 0.f;
        mw.z = (vy1 && vx0) ? wy * (1.f - wx)         : 0.f;
        mw.w = (vy1 && vx1) ? wy * wx                 : 0.f;
        *(int4*)(m + (size_t)e * 8)       = mi;
        *(float4*)(m + (size_t)e * 8 + 4) = mw;
    }
}

// ---------------------------------------------------------------------------
// Proven deformable conv kernel:
//  MET      : metadata from precomputed table / inline fallback
//  NCOMB    : 1 = direct; 2/3 = stage relu(x0+x1[+x2]) (combine partials)
//  SPLITOUT : grid (B,NS); h = blockIdx.y channel-slice [h*CIN..h*CIN+CIN);
//             pad channels (h*CIN+c >= CINW) stage ZERO (their weight reads
//             land in adjacent allocated wt rows; x contribution is 0);
//             bias only h==0; RAW partial sums to y + h*pstride.
// ---------------------------------------------------------------------------
template<int CIN, int CINW, int COUT, int K, int H, int W, int HO, int WO,
         int S, int KSEG, int NT, int NCOMB, bool SPLITOUT, bool MET>
__global__ __launch_bounds__(NT)
void deform_lds(const float* __restrict__ x0, const float* __restrict__ x1,
                const float* __restrict__ x2, const float* __restrict__ off,
                const float* __restrict__ meta, const float* __restrict__ wT,
                const float* __restrict__ bias, float* __restrict__ y,
                size_t pstride)
{
    constexpr int K2 = K * K, HW = H * W, P = HO * WO;
    constexpr int PW = ((P + 63) / 64) * 64;
    constexpr int KLEN = (K2 + KSEG - 1) / KSEG;
    constexpr int PSTR = (COUT % 2 == 0) ? COUT + 1 : COUT;
    static_assert(NT >= KSEG * PW, "NT too small for KSEG*PW");

    __shared__ __align__(16) float simg[HW * S];
    __shared__ float part[(KSEG > 1) ? (KSEG - 1) * P * PSTR : 1];

    const int tid = threadIdx.x;
    const int b   = blockIdx.x;
    const int h   = SPLITOUT ? blockIdx.y : 0;

    // ---- stage image (channel-inner, padded stride S) ----
    const size_t xoff = (size_t)b * CINW * HW + (SPLITOUT ? (size_t)h * CIN * HW : 0);
    const float* xb  = x0 + xoff;
    const float* xb1 = (NCOMB >= 2) ? (x1 + xoff) : nullptr;
    const float* xb2 = (NCOMB == 3) ? (x2 + xoff) : nullptr;
    for (int i = tid; i < CIN * HW; i += NT) {
        int c = i / HW, hw = i - c * HW;
        bool ok = true;
        if constexpr (SPLITOUT) ok = (h * CIN + c < CINW);
        float v = 0.f;
        if (ok) {
            v = xb[i];
            if constexpr (NCOMB >= 2) v += xb1[i];
            if constexpr (NCOMB == 3) v += xb2[i];
            if constexpr (NCOMB >= 2) v = fmaxf(v, 0.f);
        }
        simg[hw * S + c] = v;
    }
    __syncthreads();

    const int g  = tid / PW;
    const int p  = tid - g * PW;
    const int pc = (p < P) ? p : (P - 1);
    const bool active = (p < P);

    float acc[COUT];
#pragma unroll
    for (int o = 0; o < COUT; ++o) acc[o] = 0.f;

    if (g < KSEG) {
        if (g == 0 && (!SPLITOUT || h == 0)) {
#pragma unroll
            for (int o = 0; o < COUT; ++o) acc[o] = bias[o];
        }
        const int ho = pc / WO, wo = pc - ho * WO;
        const int kb = g * KLEN;

        auto fma_block = [&](int i00, int i01, int i10, int i11,
                             float w00, float w01, float w10, float w11,
                             int kku) {
            const float* __restrict__ r00 = simg + i00 * S;
            const float* __restrict__ r01 = simg + i01 * S;
            const float* __restrict__ r10 = simg + i10 * S;
            const float* __restrict__ r11 = simg + i11 * S;
            const float* __restrict__ wk = wT + kku * (CINW * COUT)
                                         + (SPLITOUT ? h * (CIN * COUT) : 0);
            if constexpr (CIN % 4 == 0) {
#pragma unroll
                for (int c4 = 0; c4 < CIN / 4; ++c4) {
                    const float4 v00 = *(const float4*)(r00 + c4 * 4);
                    const float4 v01 = *(const float4*)(r01 + c4 * 4);
                    const float4 v10 = *(const float4*)(r10 + c4 * 4);
                    const float4 v11 = *(const float4*)(r11 + c4 * 4);
                    float4 sa;
                    sa.x = fmaf(w00, v00.x, fmaf(w01, v01.x, fmaf(w10, v10.x, w11 * v11.x)));
                    sa.y = fmaf(w00, v00.y, fmaf(w01, v01.y, fmaf(w10, v10.y, w11 * v11.y)));
                    sa.z = fmaf(w00, v00.z, fmaf(w01, v01.z, fmaf(w10, v10.z, w11 * v11.z)));
                    sa.w = fmaf(w00, v00.w, fmaf(w01, v01.w, fmaf(w10, v10.w, w11 * v11.w)));
                    const float* __restrict__ wc = wk + (c4 * 4) * COUT;
#pragma unroll
                    for (int o = 0; o < COUT; ++o) acc[o] = fmaf(wc[o], sa.x, acc[o]);
#pragma unroll
                    for (int o = 0; o < COUT; ++o) acc[o] = fmaf(wc[COUT + o], sa.y, acc[o]);
#pragma unroll
                    for (int o = 0; o < COUT; ++o) acc[o] = fmaf(wc[2 * COUT + o], sa.z, acc[o]);
#pragma unroll
                    for (int o = 0; o < COUT; ++o) acc[o] = fmaf(wc[3 * COUT + o], sa.w, acc[o]);
                }
            } else {
#pragma unroll
                for (int c = 0; c < CIN; ++c) {
                    float sa = fmaf(w00, r00[c], fmaf(w01, r01[c],
                               fmaf(w10, r10[c], w11 * r11[c])));
#pragma unroll
                    for (int o = 0; o < COUT; ++o)
                        acc[o] = fmaf(wk[c * COUT + o], sa, acc[o]);
                }
            }
        };

        if constexpr (MET) {
            const int kf = (kb < K2) ? kb : (K2 - 1);
            int4   nmi = *(const int4*)  (meta + (size_t)(kf * P + pc) * 8);
            float4 nmw = *(const float4*)(meta + (size_t)(kf * P + pc) * 8 + 4);

#pragma unroll 1
            for (int j = 0; j < KLEN; ++j) {
                const int k  = kb + j;
                const int kk = (k < K2) ? k : (K2 - 1);
                const int4   mi  = nmi;
                const float4 mwv = nmw;
                const int kn = (k + 1 < K2) ? (k + 1) : (K2 - 1);
                nmi = *(const int4*)  (meta + (size_t)(kn * P + pc) * 8);
                nmw = *(const float4*)(meta + (size_t)(kn * P + pc) * 8 + 4);

                float w00 = mwv.x, w01 = mwv.y, w10 = mwv.z, w11 = mwv.w;
                if constexpr (K2 % KSEG != 0) {
                    const float kv = (k < K2) ? 1.f : 0.f;
                    w00 *= kv; w01 *= kv; w10 *= kv; w11 *= kv;
                }
                const int kku = __builtin_amdgcn_readfirstlane(kk);
                fma_block(mi.x, mi.y, mi.z, mi.w, w00, w01, w10, w11, kku);
            }
        } else {
            const int kf = (kb < K2) ? kb : (K2 - 1);
            float ndy = off[(2 * kf)     * P + pc];
            float ndx = off[(2 * kf + 1) * P + pc];

#pragma unroll 1
            for (int j = 0; j < KLEN; ++j) {
                const int k  = kb + j;
                const int kk = (k < K2) ? k : (K2 - 1);
                const float dy = ndy, dx = ndx;
                const int kn = (k + 1 < K2) ? (k + 1) : (K2 - 1);
                ndy = off[(2 * kn)     * P + pc];
                ndx = off[(2 * kn + 1) * P + pc];

                const int ky = kk / K, kx = kk - ky * K;
                const float py = (float)(ho + ky) + dy;
                const float px = (float)(wo + kx) + dx;
                const float y0f = floorf(py), x0f = floorf(px);
                const float wy = py - y0f, wx = px - x0f;
                const int y0 = (int)y0f, x0 = (int)x0f;
                const int y1 = y0 + 1,  x1i = x0 + 1;
                const bool vy0 = ((unsigned)y0  < (unsigned)H);
                const bool vy1 = ((unsigned)y1  < (unsigned)H);
                const bool vx0 = ((unsigned)x0  < (unsigned)W);
                const bool vx1 = ((unsigned)x1i < (unsigned)W);
                const int cy0 = min(max(y0, 0), H - 1) * W;
                const int cy1 = min(max(y1, 0), H - 1) * W;
                const int cx0 = min(max(x0, 0), W - 1);
                const int cx1 = min(max(x1i, 0), W - 1);
                float w00 = (vy0 && vx0) ? (1.f - wy) * (1.f - wx) : 0.f;
                float w01 = (vy0 && vx1) ? (1.f - wy) * wx         : 0.f;
                float w10 = (vy1 && vx0) ? wy * (1.f - wx)         : 0.f;
                float w11 = (vy1 && vx1) ? wy * wx                 : 0.f;
                if constexpr (K2 % KSEG != 0) {
                    const float kv = (k < K2) ? 1.f : 0.f;
                    w00 *= kv; w01 *= kv; w10 *= kv; w11 *= kv;
                }
                const int kku = __builtin_amdgcn_readfirstlane(kk);
                fma_block(cy0 + cx0, cy0 + cx1, cy1 + cx0, cy1 + cx1,
                          w00, w01, w10, w11, kku);
            }
        }

        if (g > 0 && active) {
#pragma unroll
            for (int o = 0; o < COUT; ++o)
                part[(g - 1) * (P * PSTR) + p * PSTR + o] = acc[o];
        }
    }

    if constexpr (KSEG > 1) __syncthreads();

    if (g == 0 && active) {
        if constexpr (KSEG > 1) {
#pragma unroll
            for (int gg = 1; gg < KSEG; ++gg)
#pragma unroll
                for (int o = 0; o < COUT; ++o)
                    acc[o] += part[(gg - 1) * (P * PSTR) + p * PSTR + o];
        }
        float* yb = y + (SPLITOUT ? (size_t)h * pstride : 0) + (size_t)b * COUT * P;
#pragma unroll
        for (int o = 0; o < COUT; ++o)
            yb[o * P + p] = SPLITOUT ? acc[o] : fmaxf(acc[o], 0.f);
    }
}

// ---------------------------------------------------------------------------
// Fused head: perm gather + FC(676->256) + ReLU + FC(256->10).
// ---------------------------------------------------------------------------
__global__ __launch_bounds__(256)
void fc_head(const float* __restrict__ x6, const float* __restrict__ w7,
             const float* __restrict__ b7, const float* __restrict__ w8,
             const float* __restrict__ b8, const int* __restrict__ perm,
             float* __restrict__ out)
{
    constexpr int F = 676;
    __shared__ float sx[F];
    __shared__ float sh[256];

    const int tid = threadIdx.x;
    const int b   = blockIdx.x;

    for (int i = tid; i < F; i += 256) {
        int c = i / 169, p = i - c * 169;
        sx[i] = x6[(size_t)b * F + c * 169 + perm[p]];
    }
    __syncthreads();

    float acc = b7[tid];
#pragma unroll 4
    for (int i = 0; i < F; ++i)
        acc = fmaf(sx[i], w7[i * 256 + tid], acc);
    sh[tid] = fmaxf(acc, 0.f);
    __syncthreads();

    if (tid < 10) {
        float a = b8[tid];
#pragma unroll 8
        for (int j = 0; j < 256; ++j)
            a = fmaf(sh[j], w8[j * 10 + tid], a);
        out[(size_t)b * 10 + tid] = a;
    }
}

// ---------------------------------------------------------------------------
extern "C" void kernel_launch(void* const* d_in, const int* in_sizes, int n_in,
                              void* d_out, int out_size, void* d_ws, size_t ws_size,
                              hipStream_t stream)
{
    const float* x    = (const float*)d_in[0];
    const float* off1 = (const float*)d_in[1];
    const float* w1   = (const float*)d_in[2];
    const float* b1   = (const float*)d_in[3];
    const float* off2 = (const float*)d_in[4];
    const float* w2   = (const float*)d_in[5];
    const float* b2   = (const float*)d_in[6];
    const float* off3 = (const float*)d_in[7];
    const float* w3   = (const float*)d_in[8];
    const float* b3   = (const float*)d_in[9];
    const float* off4 = (const float*)d_in[10];
    const float* w4   = (const float*)d_in[11];
    const float* b4   = (const float*)d_in[12];
    const float* off5 = (const float*)d_in[13];
    const float* w5   = (const float*)d_in[14];
    const float* b5   = (const float*)d_in[15];
    const float* off6 = (const float*)d_in[16];
    const float* w6   = (const float*)d_in[17];
    const float* b6   = (const float*)d_in[18];
    const float* w7   = (const float*)d_in[19];
    const float* b7   = (const float*)d_in[20];
    const float* w8   = (const float*)d_in[21];
    const float* b8   = (const float*)d_in[22];
    const int*   perm = (const int*)d_in[23];
    float* out = (float*)d_out;

    // ws layout (floats):
    //   wt   @ 0           (33,792)
    //   buf0 @ 33,792      (3,936,256)   a1 / a3(p0L3) / a5
    //   buf1 @ 3,970,048   (6,889,472)   a2(p0L2) / a4-partials / a6
    //   p1L3 @ 10,859,520  (2,560,000)   = a3 + X, X = 10,825,728
    //   p1L2 @ 13,419,520  (6,889,472)
    //   meta @ 20,308,992  (453,424)
    //   p2L3 @ 21,685,248  (2,560,000)   = a3 + 2X  [gate: split3]
    const int woff[6] = {0, 144, 4752, 17552, 30096, 33296};
    float* ws   = (float*)d_ws;
    float* wt   = ws;
    float* buf0 = ws + 33792;
    float* buf1 = buf0 + 3936256;

    float* a1   = buf0;
    float* a2   = buf1;
    float* p1L2 = ws + 13419520;
    float* a3   = buf0;
    float* p1L3 = ws + 10859520;
    float* a4p0 = buf1;
    float* a4p1 = buf1 + 1478656;
    float* a5   = buf0;
    float* a6   = buf1;
    float* meta = ws + 20308992;

    const int mbase[6] = {0, 8649, 16218, 31843, 49532, 55157};
    const int MTOT = 56678;

    const bool splitL3 = (ws_size >= (size_t)13419520 * sizeof(float));
    const bool splitL2 = (ws_size >= (size_t)20308992 * sizeof(float));
    const bool metaOK  = (ws_size >= (size_t)(20308992 + MTOT * 8) * sizeof(float));
    const bool split3  = (ws_size >= (size_t)24245248 * sizeof(float));
    const size_t X      = 10825728;           // a3 -> p1L3 -> p2L3 stride
    const size_t pstrL2 = (size_t)(p1L2 - a2);
    const size_t pstrL4 = 1478656;

    WtArgs wa;
    wa.src[0] = w1; wa.src[1] = w2; wa.src[2] = w3;
    wa.src[3] = w4; wa.src[4] = w5; wa.src[5] = w6;
    const int cos[6] = {16, 32, 16, 16, 8, 4};
    const int cis[6] = {1, 16, 32, 16, 16, 8};
    const int k2s[6] = {9, 9, 25, 49, 25, 9};
    for (int i = 0; i < 6; ++i) {
        wa.co[i] = cos[i]; wa.ci[i] = cis[i];
        wa.k2[i] = k2s[i]; wa.dstoff[i] = woff[i];
    }
    transpose_weights<<<dim3(6), dim3(256), 0, stream>>>(wa, wt);

    const dim3 g1(256), g2(256, 2), g3(256, 3);

    if (metaOK) {
        MetaArgs ma;
        ma.off[0] = off1; ma.off[1] = off2; ma.off[2] = off3;
        ma.off[3] = off4; ma.off[4] = off5; ma.off[5] = off6;
        const int Ps[6]  = {961, 841, 625, 361, 225, 169};
        const int Ks[6]  = {3, 3, 5, 7, 5, 3};
        const int WOs[6] = {31, 29, 25, 19, 15, 13};
        const int Hs[6]  = {33, 31, 29, 25, 19, 15};
        const int Ws_[6] = {33, 31, 29, 25, 19, 15};
        for (int i = 0; i < 6; ++i) {
            ma.P[i] = Ps[i]; ma.K[i] = Ks[i]; ma.WO[i] = WOs[i];
            ma.H[i] = Hs[i]; ma.W[i] = Ws_[i]; ma.base[i] = mbase[i];
        }
        build_meta<<<dim3(64, 6), dim3(256), 0, stream>>>(ma, meta);

        // <CIN,CINW,COUT,K,H,W,HO,WO,S,KSEG,NT,NCOMB,SPLITOUT,MET>
        deform_lds< 1,  1, 16, 3, 33, 33, 31, 31,  1, 1, 1024, 1, false, true>
            <<<g1, dim3(1024), 0, stream>>>(x, nullptr, nullptr, off1, meta + (size_t)mbase[0]*8, wt + woff[0], b1, a1, 0);
        deform_lds< 8, 16, 32, 3, 31, 31, 29, 29, 12, 1,  896, 1, true,  true>
            <<<g2, dim3(896),  0, stream>>>(a1, nullptr, nullptr, off2, meta + (size_t)mbase[1]*8, wt + woff[1], b2, a2, pstrL2);

        if (split3) {
            // L3 3-way split: CIN slices {12,12,8+4pad}, 40.4 KB LDS -> 3 blocks/CU
            deform_lds<12, 32, 16, 5, 29, 29, 25, 25, 12, 1,  640, 2, true,  true>
                <<<g3, dim3(640),  0, stream>>>(a2, p1L2, nullptr, off3, meta + (size_t)mbase[2]*8, wt + woff[2], b3, a3, X);
            deform_lds< 8, 16, 16, 7, 25, 25, 19, 19, 12, 2,  768, 3, true,  true>
                <<<g2, dim3(768),  0, stream>>>(a3, a3 + X, a3 + 2 * X, off4, meta + (size_t)mbase[3]*8, wt + woff[3], b4, a4p0, pstrL4);
        } else {
            deform_lds<16, 32, 16, 5, 29, 29, 25, 25, 20, 1,  640, 2, true,  true>
                <<<g2, dim3(640),  0, stream>>>(a2, p1L2, nullptr, off3, meta + (size_t)mbase[2]*8, wt + woff[2], b3, a3, X);
            deform_lds< 8, 16, 16, 7, 25, 25, 19, 19, 12, 2,  768, 2, true,  true>
                <<<g2, dim3(768),  0, stream>>>(a3, a3 + X, nullptr, off4, meta + (size_t)mbase[3]*8, wt + woff[3], b4, a4p0, pstrL4);
        }

        deform_lds<16, 16,  8, 5, 19, 19, 15, 15, 20, 4, 1024, 2, false, true>
            <<<g1, dim3(1024), 0, stream>>>(a4p0, a4p1, nullptr, off5, meta + (size_t)mbase[4]*8, wt + woff[4], b5, a5, 0);
        deform_lds< 8,  8,  4, 3, 15, 15, 13, 13, 12, 5,  960, 1, false, true>
            <<<g1, dim3(960),  0, stream>>>(a5, nullptr, nullptr, off6, meta + (size_t)mbase[5]*8, wt + woff[5], b6, a6, 0);
    } else {
        // round-10 fallback (MET=false)
        deform_lds< 1,  1, 16, 3, 33, 33, 31, 31,  1, 1, 1024, 1, false, false>
            <<<g1, dim3(1024), 0, stream>>>(x, nullptr, nullptr, off1, nullptr, wt + woff[0], b1, a1, 0);
        if (splitL2) {
            deform_lds< 8, 16, 32, 3, 31, 31, 29, 29, 12, 1, 1024, 1, true, false>
                <<<g2, dim3(1024), 0, stream>>>(a1, nullptr, nullptr, off2, nullptr, wt + woff[1], b2, a2, pstrL2);
        } else {
            deform_lds<16, 16, 32, 3, 31, 31, 29, 29, 20, 1, 1024, 1, false, false>
                <<<g1, dim3(1024), 0, stream>>>(a1, nullptr, nullptr, off2, nullptr, wt + woff[1], b2, a2, 0);
        }
        if (splitL3) {
            if (splitL2) {
                deform_lds<16, 32, 16, 5, 29, 29, 25, 25, 20, 1, 1024, 2, true, false>
                    <<<g2, dim3(1024), 0, stream>>>(a2, p1L2, nullptr, off3, nullptr, wt + woff[2], b3, a3, X);
            } else {
                deform_lds<16, 32, 16, 5, 29, 29, 25, 25, 20, 1, 1024, 1, true, false>
                    <<<g2, dim3(1024), 0, stream>>>(a2, nullptr, nullptr, off3, nullptr, wt + woff[2], b3, a3, X);
            }
            deform_lds< 8, 16, 16, 7, 25, 25, 19, 19, 12, 2,  768, 2, true, false>
                <<<g2, dim3(768),  0, stream>>>(a3, a3 + X, nullptr, off4, nullptr, wt + woff[3], b4, a4p0, pstrL4);
        } else {
            deform_lds<32, 32, 16, 5, 29, 29, 25, 25, 36, 1, 1024, 1, false, false>
                <<<g1, dim3(1024), 0, stream>>>(a2, nullptr, nullptr, off3, nullptr, wt + woff[2], b3, a3, 0);
            deform_lds< 8, 16, 16, 7, 25, 25, 19, 19, 12, 2,  768, 1, true, false>
                <<<g2, dim3(768),  0, stream>>>(a3, nullptr, nullptr, off4, nullptr, wt + woff[3], b4, a4p0, pstrL4);
        }
        deform_lds<16, 16,  8, 5, 19, 19, 15, 15, 20, 4, 1024, 2, false, false>
            <<<g1, dim3(1024), 0, stream>>>(a4p0, a4p1, nullptr, off5, nullptr, wt + woff[4], b5, a5, 0);
        deform_lds< 8,  8,  4, 3, 15, 15, 13, 13, 12, 5,  960, 1, false, false>
            <<<g1, dim3(960),  0, stream>>>(a5, nullptr, nullptr, off6, nullptr, wt + woff[5], b6, a6, 0);
    }

    fc_head<<<dim3(256), dim3(256), 0, stream>>>(a6, w7, b7, w8, b8, perm, out);
}

// Round 13
// 256.456 us; speedup vs baseline: 2.0143x; 1.0486x over previous
//
#include <hip/hip_runtime.h>

template<int N> struct IC { static constexpr int val = N; };

// ---------------------------------------------------------------------------
// Weight transpose: w[o][c][k] -> wT[(k*ci + c)*co + o].
// ---------------------------------------------------------------------------
struct WtArgs { const float* src[6]; int co[6], ci[6], k2[6], dstoff[6]; };

__global__ __launch_bounds__(256)
void transpose_weights(WtArgs a, float* __restrict__ dst0)
{
    const int L = blockIdx.x;
    const float* __restrict__ s = a.src[L];
    float* __restrict__ d = dst0 + a.dstoff[L];
    const int co = a.co[L], ci = a.ci[L], k2 = a.k2[L];
    const int n = co * ci * k2;
    for (int i = threadIdx.x; i < n; i += 256) {
        int k = i % k2;
        int c = (i / k2) % ci;
        int o = i / (k2 * ci);
        d[(k * ci + c) * co + o] = s[i];
    }
}

// ---------------------------------------------------------------------------
// Batch-invariant bilinear metadata tables: entry e = k*P+p holds
// {int4 corner-pixel-indices, float4 corner-weights} (32 B).
// ---------------------------------------------------------------------------
struct MetaArgs { const float* off[6]; int P[6], K[6], WO[6], H[6], W[6], base[6]; };

__global__ __launch_bounds__(256)
void build_meta(MetaArgs a, float* __restrict__ meta0)
{
    const int L = blockIdx.y;
    const float* __restrict__ off = a.off[L];
    const int P = a.P[L], K = a.K[L], WOv = a.WO[L], H = a.H[L], Wv = a.W[L];
    const int N = P * K * K;
    float* __restrict__ m = meta0 + (size_t)a.base[L] * 8;
    for (int e = blockIdx.x * 256 + threadIdx.x; e < N; e += gridDim.x * 256) {
        const int k = e / P, p = e - k * P;
        const int ho = p / WOv, wo = p - ho * WOv;
        const int ky = k / K, kx = k - ky * K;
        const float dy = off[(2 * k)     * P + p];
        const float dx = off[(2 * k + 1) * P + p];
        const float py = (float)(ho + ky) + dy;
        const float px = (float)(wo + kx) + dx;
        const float y0f = floorf(py), x0f = floorf(px);
        const float wy = py - y0f, wx = px - x0f;
        const int y0 = (int)y0f, x0 = (int)x0f;
        const int y1 = y0 + 1,  x1 = x0 + 1;
        const bool vy0 = ((unsigned)y0 < (unsigned)H);
        const bool vy1 = ((unsigned)y1 < (unsigned)H);
        const bool vx0 = ((unsigned)x0 < (unsigned)Wv);
        const bool vx1 = ((unsigned)x1 < (unsigned)Wv);
        const int cy0 = min(max(y0, 0), H - 1) * Wv;
        const int cy1 = min(max(y1, 0), H - 1) * Wv;
        const int cx0 = min(max(x0, 0), Wv - 1);
        const int cx1 = min(max(x1, 0), Wv - 1);
        int4 mi;
        mi.x = cy0 + cx0; mi.y = cy0 + cx1; mi.z = cy1 + cx0; mi.w = cy1 + cx1;
        float4 mw;
        mw.x = (vy0 && vx0) ? (1.f - wy) * (1.f - wx) : 0.f;
        mw.y = (vy0 && vx1) ? (1.f - wy) * wx         : 0.f;
        mw.z = (vy1 && vx0) ? wy * (1.f - wx)         : 0.f;
        mw.w = (vy1 && vx1) ? wy * wx                 : 0.f;
        *(int4*)(m + (size_t)e * 8)       = mi;
        *(float4*)(m + (size_t)e * 8 + 4) = mw;
    }
}

// ---------------------------------------------------------------------------
// Proven deformable conv kernel:
//  MET      : metadata from precomputed table / inline fallback
//  NCOMB    : 1 = direct; 2/3 = stage relu(x0+x1[+x2]) (combine partials)
//  SPLITOUT : grid (B,NS); h = blockIdx.y channel-slice [h*CIN..h*CIN+CIN);
//             pad channels stage ZERO; bias only h==0; RAW partials to
//             y + h*pstride.
//  NSL/CINL : heterogeneous last slice — slice NSL-1 has CINL real channels
//             and its compute loop reads only ceil(CINL/4) float4 groups
//             (no pad-channel LDS reads). CINL=0 -> uniform slices.
// ---------------------------------------------------------------------------
template<int CIN, int CINW, int COUT, int K, int H, int W, int HO, int WO,
         int S, int KSEG, int NT, int NCOMB, bool SPLITOUT, bool MET,
         int NSL = 1, int CINL = 0>
__global__ __launch_bounds__(NT)
void deform_lds(const float* __restrict__ x0, const float* __restrict__ x1,
                const float* __restrict__ x2, const float* __restrict__ off,
                const float* __restrict__ meta, const float* __restrict__ wT,
                const float* __restrict__ bias, float* __restrict__ y,
                size_t pstride)
{
    constexpr int K2 = K * K, HW = H * W, P = HO * WO;
    constexpr int PW = ((P + 63) / 64) * 64;
    constexpr int KLEN = (K2 + KSEG - 1) / KSEG;
    constexpr int PSTR = (COUT % 2 == 0) ? COUT + 1 : COUT;
    static_assert(NT >= KSEG * PW, "NT too small for KSEG*PW");

    __shared__ __align__(16) float simg[HW * S];
    __shared__ float part[(KSEG > 1) ? (KSEG - 1) * P * PSTR : 1];

    const int tid = threadIdx.x;
    const int b   = blockIdx.x;
    const int h   = SPLITOUT ? blockIdx.y : 0;

    // ---- stage image (channel-inner, padded stride S) ----
    const size_t xoff = (size_t)b * CINW * HW + (SPLITOUT ? (size_t)h * CIN * HW : 0);
    const float* xb  = x0 + xoff;
    const float* xb1 = (NCOMB >= 2) ? (x1 + xoff) : nullptr;
    const float* xb2 = (NCOMB == 3) ? (x2 + xoff) : nullptr;
    for (int i = tid; i < CIN * HW; i += NT) {
        int c = i / HW, hw = i - c * HW;
        bool ok = true;
        if constexpr (SPLITOUT) ok = (h * CIN + c < CINW);
        float v = 0.f;
        if (ok) {
            v = xb[i];
            if constexpr (NCOMB >= 2) v += xb1[i];
            if constexpr (NCOMB == 3) v += xb2[i];
            if constexpr (NCOMB >= 2) v = fmaxf(v, 0.f);
        }
        simg[hw * S + c] = v;
    }
    __syncthreads();

    const int g  = tid / PW;
    const int p  = tid - g * PW;
    const int pc = (p < P) ? p : (P - 1);
    const bool active = (p < P);

    float acc[COUT];
#pragma unroll
    for (int o = 0; o < COUT; ++o) acc[o] = 0.f;

    if (g < KSEG) {
        if (g == 0 && (!SPLITOUT || h == 0)) {
#pragma unroll
            for (int o = 0; o < COUT; ++o) acc[o] = bias[o];
        }
        const int ho = pc / WO, wo = pc - ho * WO;
        const int kb = g * KLEN;

        auto run = [&](auto nc4tag) {
            constexpr int NC4 = decltype(nc4tag)::val;

            auto fma_block = [&](int i00, int i01, int i10, int i11,
                                 float w00, float w01, float w10, float w11,
                                 int kku) {
                const float* __restrict__ r00 = simg + i00 * S;
                const float* __restrict__ r01 = simg + i01 * S;
                const float* __restrict__ r10 = simg + i10 * S;
                const float* __restrict__ r11 = simg + i11 * S;
                const float* __restrict__ wk = wT + kku * (CINW * COUT)
                                             + (SPLITOUT ? h * (CIN * COUT) : 0);
                if constexpr (CIN % 4 == 0) {
#pragma unroll
                    for (int c4 = 0; c4 < NC4; ++c4) {
                        const float4 v00 = *(const float4*)(r00 + c4 * 4);
                        const float4 v01 = *(const float4*)(r01 + c4 * 4);
                        const float4 v10 = *(const float4*)(r10 + c4 * 4);
                        const float4 v11 = *(const float4*)(r11 + c4 * 4);
                        float4 sa;
                        sa.x = fmaf(w00, v00.x, fmaf(w01, v01.x, fmaf(w10, v10.x, w11 * v11.x)));
                        sa.y = fmaf(w00, v00.y, fmaf(w01, v01.y, fmaf(w10, v10.y, w11 * v11.y)));
                        sa.z = fmaf(w00, v00.z, fmaf(w01, v01.z, fmaf(w10, v10.z, w11 * v11.z)));
                        sa.w = fmaf(w00, v00.w, fmaf(w01, v01.w, fmaf(w10, v10.w, w11 * v11.w)));
                        const float* __restrict__ wc = wk + (c4 * 4) * COUT;
#pragma unroll
                        for (int o = 0; o < COUT; ++o) acc[o] = fmaf(wc[o], sa.x, acc[o]);
#pragma unroll
                        for (int o = 0; o < COUT; ++o) acc[o] = fmaf(wc[COUT + o], sa.y, acc[o]);
#pragma unroll
                        for (int o = 0; o < COUT; ++o) acc[o] = fmaf(wc[2 * COUT + o], sa.z, acc[o]);
#pragma unroll
                        for (int o = 0; o < COUT; ++o) acc[o] = fmaf(wc[3 * COUT + o], sa.w, acc[o]);
                    }
                } else {
#pragma unroll
                    for (int c = 0; c < CIN; ++c) {
                        float sa = fmaf(w00, r00[c], fmaf(w01, r01[c],
                                   fmaf(w10, r10[c], w11 * r11[c])));
#pragma unroll
                        for (int o = 0; o < COUT; ++o)
                            acc[o] = fmaf(wk[c * COUT + o], sa, acc[o]);
                    }
                }
            };

            if constexpr (MET) {
                const int kf = (kb < K2) ? kb : (K2 - 1);
                int4   nmi = *(const int4*)  (meta + (size_t)(kf * P + pc) * 8);
                float4 nmw = *(const float4*)(meta + (size_t)(kf * P + pc) * 8 + 4);

#pragma unroll 1
                for (int j = 0; j < KLEN; ++j) {
                    const int k  = kb + j;
                    const int kk = (k < K2) ? k : (K2 - 1);
                    const int4   mi  = nmi;
                    const float4 mwv = nmw;
                    const int kn = (k + 1 < K2) ? (k + 1) : (K2 - 1);
                    nmi = *(const int4*)  (meta + (size_t)(kn * P + pc) * 8);
                    nmw = *(const float4*)(meta + (size_t)(kn * P + pc) * 8 + 4);

                    float w00 = mwv.x, w01 = mwv.y, w10 = mwv.z, w11 = mwv.w;
                    if constexpr (K2 % KSEG != 0) {
                        const float kv = (k < K2) ? 1.f : 0.f;
                        w00 *= kv; w01 *= kv; w10 *= kv; w11 *= kv;
                    }
                    const int kku = __builtin_amdgcn_readfirstlane(kk);
                    fma_block(mi.x, mi.y, mi.z, mi.w, w00, w01, w10, w11, kku);
                }
            } else {
                const int kf = (kb < K2) ? kb : (K2 - 1);
                float ndy = off[(2 * kf)     * P + pc];
                float ndx = off[(2 * kf + 1) * P + pc];

#pragma unroll 1
                for (int j = 0; j < KLEN; ++j) {
                    const int k  = kb + j;
                    const int kk = (k < K2) ? k : (K2 - 1);
                    const float dy = ndy, dx = ndx;
                    const int kn = (k + 1 < K2) ? (k + 1) : (K2 - 1);
                    ndy = off[(2 * kn)     * P + pc];
                    ndx = off[(2 * kn + 1) * P + pc];

                    const int ky = kk / K, kx = kk - ky * K;
                    const float py = (float)(ho + ky) + dy;
                    const float px = (float)(wo + kx) + dx;
                    const float y0f = floorf(py), x0f = floorf(px);
                    const float wy = py - y0f, wx = px - x0f;
                    const int y0 = (int)y0f, x0 = (int)x0f;
                    const int y1 = y0 + 1,  x1i = x0 + 1;
                    const bool vy0 = ((unsigned)y0  < (unsigned)H);
                    const bool vy1 = ((unsigned)y1  < (unsigned)H);
                    const bool vx0 = ((unsigned)x0  < (unsigned)W);
                    const bool vx1 = ((unsigned)x1i < (unsigned)W);
                    const int cy0 = min(max(y0, 0), H - 1) * W;
                    const int cy1 = min(max(y1, 0), H - 1) * W;
                    const int cx0 = min(max(x0, 0), W - 1);
                    const int cx1 = min(max(x1i, 0), W - 1);
                    float w00 = (vy0 && vx0) ? (1.f - wy) * (1.f - wx) : 0.f;
                    float w01 = (vy0 && vx1) ? (1.f - wy) * wx         : 0.f;
                    float w10 = (vy1 && vx0) ? wy * (1.f - wx)         : 0.f;
                    float w11 = (vy1 && vx1) ? wy * wx                 : 0.f;
                    if constexpr (K2 % KSEG != 0) {
                        const float kv = (k < K2) ? 1.f : 0.f;
                        w00 *= kv; w01 *= kv; w10 *= kv; w11 *= kv;
                    }
                    const int kku = __builtin_amdgcn_readfirstlane(kk);
                    fma_block(cy0 + cx0, cy0 + cx1, cy1 + cx0, cy1 + cx1,
                              w00, w01, w10, w11, kku);
                }
            }
        };

        if constexpr (SPLITOUT && CINL > 0) {
            if (h == NSL - 1) run(IC<(CINL + 3) / 4>{});
            else              run(IC<(CIN + 3) / 4>{});
        } else {
            run(IC<(CIN + 3) / 4>{});
        }

        if (g > 0 && active) {
#pragma unroll
            for (int o = 0; o < COUT; ++o)
                part[(g - 1) * (P * PSTR) + p * PSTR + o] = acc[o];
        }
    }

    if constexpr (KSEG > 1) __syncthreads();

    if (g == 0 && active) {
        if constexpr (KSEG > 1) {
#pragma unroll
            for (int gg = 1; gg < KSEG; ++gg)
#pragma unroll
                for (int o = 0; o < COUT; ++o)
                    acc[o] += part[(gg - 1) * (P * PSTR) + p * PSTR + o];
        }
        float* yb = y + (SPLITOUT ? (size_t)h * pstride : 0) + (size_t)b * COUT * P;
#pragma unroll
        for (int o = 0; o < COUT; ++o)
            yb[o * P + p] = SPLITOUT ? acc[o] : fmaxf(acc[o], 0.f);
    }
}

// ---------------------------------------------------------------------------
// Fused head: perm gather + FC(676->256) + ReLU + FC(256->10).
// ---------------------------------------------------------------------------
__global__ __launch_bounds__(256)
void fc_head(const float* __restrict__ x6, const float* __restrict__ w7,
             const float* __restrict__ b7, const float* __restrict__ w8,
             const float* __restrict__ b8, const int* __restrict__ perm,
             float* __restrict__ out)
{
    constexpr int F = 676;
    __shared__ float sx[F];
    __shared__ float sh[256];

    const int tid = threadIdx.x;
    const int b   = blockIdx.x;

    for (int i = tid; i < F; i += 256) {
        int c = i / 169, p = i - c * 169;
        sx[i] = x6[(size_t)b * F + c * 169 + perm[p]];
    }
    __syncthreads();

    float acc = b7[tid];
#pragma unroll 4
    for (int i = 0; i < F; ++i)
        acc = fmaf(sx[i], w7[i * 256 + tid], acc);
    sh[tid] = fmaxf(acc, 0.f);
    __syncthreads();

    if (tid < 10) {
        float a = b8[tid];
#pragma unroll 8
        for (int j = 0; j < 256; ++j)
            a = fmaf(sh[j], w8[j * 10 + tid], a);
        out[(size_t)b * 10 + tid] = a;
    }
}

// ---------------------------------------------------------------------------
extern "C" void kernel_launch(void* const* d_in, const int* in_sizes, int n_in,
                              void* d_out, int out_size, void* d_ws, size_t ws_size,
                              hipStream_t stream)
{
    const float* x    = (const float*)d_in[0];
    const float* off1 = (const float*)d_in[1];
    const float* w1   = (const float*)d_in[2];
    const float* b1   = (const float*)d_in[3];
    const float* off2 = (const float*)d_in[4];
    const float* w2   = (const float*)d_in[5];
    const float* b2   = (const float*)d_in[6];
    const float* off3 = (const float*)d_in[7];
    const float* w3   = (const float*)d_in[8];
    const float* b3   = (const float*)d_in[9];
    const float* off4 = (const float*)d_in[10];
    const float* w4   = (const float*)d_in[11];
    const float* b4   = (const float*)d_in[12];
    const float* off5 = (const float*)d_in[13];
    const float* w5   = (const float*)d_in[14];
    const float* b5   = (const float*)d_in[15];
    const float* off6 = (const float*)d_in[16];
    const float* w6   = (const float*)d_in[17];
    const float* b6   = (const float*)d_in[18];
    const float* w7   = (const float*)d_in[19];
    const float* b7   = (const float*)d_in[20];
    const float* w8   = (const float*)d_in[21];
    const float* b8   = (const float*)d_in[22];
    const int*   perm = (const int*)d_in[23];
    float* out = (float*)d_out;

    // ws layout (floats):
    //   wt   @ 0           (33,792)
    //   buf0 @ 33,792      (3,936,256)   a1 / a3(p0L3) / a5
    //   buf1 @ 3,970,048   (6,889,472)   a2(p0L2) / a4-partials / a6
    //   p1L3 @ 10,859,520  (2,560,000)   = a3 + X, X = 10,825,728
    //   p1L2 @ 13,419,520  (6,889,472)
    //   meta @ 20,308,992  (453,424)
    //   p2L3 @ 21,685,248  (2,560,000)   = a3 + 2X  [gate: split3]
    const int woff[6] = {0, 144, 4752, 17552, 30096, 33296};
    float* ws   = (float*)d_ws;
    float* wt   = ws;
    float* buf0 = ws + 33792;
    float* buf1 = buf0 + 3936256;

    float* a1   = buf0;
    float* a2   = buf1;
    float* p1L2 = ws + 13419520;
    float* a3   = buf0;
    float* p1L3 = ws + 10859520;
    float* a4p0 = buf1;
    float* a4p1 = buf1 + 1478656;
    float* a5   = buf0;
    float* a6   = buf1;
    float* meta = ws + 20308992;

    const int mbase[6] = {0, 8649, 16218, 31843, 49532, 55157};
    const int MTOT = 56678;

    const bool splitL3 = (ws_size >= (size_t)13419520 * sizeof(float));
    const bool splitL2 = (ws_size >= (size_t)20308992 * sizeof(float));
    const bool metaOK  = (ws_size >= (size_t)(20308992 + MTOT * 8) * sizeof(float));
    const bool split3  = (ws_size >= (size_t)24245248 * sizeof(float));
    const size_t X      = 10825728;           // a3 -> p1L3 -> p2L3 stride
    const size_t pstrL2 = (size_t)(p1L2 - a2);
    const size_t pstrL4 = 1478656;

    WtArgs wa;
    wa.src[0] = w1; wa.src[1] = w2; wa.src[2] = w3;
    wa.src[3] = w4; wa.src[4] = w5; wa.src[5] = w6;
    const int cos[6] = {16, 32, 16, 16, 8, 4};
    const int cis[6] = {1, 16, 32, 16, 16, 8};
    const int k2s[6] = {9, 9, 25, 49, 25, 9};
    for (int i = 0; i < 6; ++i) {
        wa.co[i] = cos[i]; wa.ci[i] = cis[i];
        wa.k2[i] = k2s[i]; wa.dstoff[i] = woff[i];
    }
    transpose_weights<<<dim3(6), dim3(256), 0, stream>>>(wa, wt);

    const dim3 g1(256), g2(256, 2), g3(256, 3);

    if (metaOK) {
        MetaArgs ma;
        ma.off[0] = off1; ma.off[1] = off2; ma.off[2] = off3;
        ma.off[3] = off4; ma.off[4] = off5; ma.off[5] = off6;
        const int Ps[6]  = {961, 841, 625, 361, 225, 169};
        const int Ks[6]  = {3, 3, 5, 7, 5, 3};
        const int WOs[6] = {31, 29, 25, 19, 15, 13};
        const int Hs[6]  = {33, 31, 29, 25, 19, 15};
        const int Ws_[6] = {33, 31, 29, 25, 19, 15};
        for (int i = 0; i < 6; ++i) {
            ma.P[i] = Ps[i]; ma.K[i] = Ks[i]; ma.WO[i] = WOs[i];
            ma.H[i] = Hs[i]; ma.W[i] = Ws_[i]; ma.base[i] = mbase[i];
        }
        build_meta<<<dim3(64, 6), dim3(256), 0, stream>>>(ma, meta);

        // <CIN,CINW,COUT,K,H,W,HO,WO,S,KSEG,NT,NCOMB,SPLITOUT,MET[,NSL,CINL]>
        deform_lds< 1,  1, 16, 3, 33, 33, 31, 31,  1, 1, 1024, 1, false, true>
            <<<g1, dim3(1024), 0, stream>>>(x, nullptr, nullptr, off1, meta + (size_t)mbase[0]*8, wt + woff[0], b1, a1, 0);
        deform_lds< 8, 16, 32, 3, 31, 31, 29, 29, 12, 1,  896, 1, true,  true>
            <<<g2, dim3(896),  0, stream>>>(a1, nullptr, nullptr, off2, meta + (size_t)mbase[1]*8, wt + woff[1], b2, a2, pstrL2);

        if (split3) {
            // L3 3-way split {12,12,8}: last slice reads only 2 c4 groups
            deform_lds<12, 32, 16, 5, 29, 29, 25, 25, 12, 1,  640, 2, true,  true, 3, 8>
                <<<g3, dim3(640),  0, stream>>>(a2, p1L2, nullptr, off3, meta + (size_t)mbase[2]*8, wt + woff[2], b3, a3, X);
            deform_lds< 8, 16, 16, 7, 25, 25, 19, 19, 12, 2,  768, 3, true,  true>
                <<<g2, dim3(768),  0, stream>>>(a3, a3 + X, a3 + 2 * X, off4, meta + (size_t)mbase[3]*8, wt + woff[3], b4, a4p0, pstrL4);
        } else {
            deform_lds<16, 32, 16, 5, 29, 29, 25, 25, 20, 1,  640, 2, true,  true>
                <<<g2, dim3(640),  0, stream>>>(a2, p1L2, nullptr, off3, meta + (size_t)mbase[2]*8, wt + woff[2], b3, a3, X);
            deform_lds< 8, 16, 16, 7, 25, 25, 19, 19, 12, 2,  768, 2, true,  true>
                <<<g2, dim3(768),  0, stream>>>(a3, a3 + X, nullptr, off4, meta + (size_t)mbase[3]*8, wt + woff[3], b4, a4p0, pstrL4);
        }

        deform_lds<16, 16,  8, 5, 19, 19, 15, 15, 20, 4, 1024, 2, false, true>
            <<<g1, dim3(1024), 0, stream>>>(a4p0, a4p1, nullptr, off5, meta + (size_t)mbase[4]*8, wt + woff[4], b5, a5, 0);
        deform_lds< 8,  8,  4, 3, 15, 15, 13, 13, 12, 5,  960, 1, false, true>
            <<<g1, dim3(960),  0, stream>>>(a5, nullptr, nullptr, off6, meta + (size_t)mbase[5]*8, wt + woff[5], b6, a6, 0);
    } else {
        // round-10 fallback (MET=false)
        deform_lds< 1,  1, 16, 3, 33, 33, 31, 31,  1, 1, 1024, 1, false, false>
            <<<g1, dim3(1024), 0, stream>>>(x, nullptr, nullptr, off1, nullptr, wt + woff[0], b1, a1, 0);
        if (splitL2) {
            deform_lds< 8, 16, 32, 3, 31, 31, 29, 29, 12, 1, 1024, 1, true, false>
                <<<g2, dim3(1024), 0, stream>>>(a1, nullptr, nullptr, off2, nullptr, wt + woff[1], b2, a2, pstrL2);
        } else {
            deform_lds<16, 16, 32, 3, 31, 31, 29, 29, 20, 1, 1024, 1, false, false>
                <<<g1, dim3(1024), 0, stream>>>(a1, nullptr, nullptr, off2, nullptr, wt + woff[1], b2, a2, 0);
        }
        if (splitL3) {
            if (splitL2) {
                deform_lds<16, 32, 16, 5, 29, 29, 25, 25, 20, 1, 1024, 2, true, false>
                    <<<g2, dim3(1024), 0, stream>>>(a2, p1L2, nullptr, off3, nullptr, wt + woff[2], b3, a3, X);
            } else {
                deform_lds<16, 32, 16, 5, 29, 29, 25, 25, 20, 1, 1024, 1, true, false>
                    <<<g2, dim3(1024), 0, stream>>>(a2, nullptr, nullptr, off3, nullptr, wt + woff[2], b3, a3, X);
            }
            deform_lds< 8, 16, 16, 7, 25, 25, 19, 19, 12, 2,  768, 2, true, false>
                <<<g2, dim3(768),  0, stream>>>(a3, a3 + X, nullptr, off4, nullptr, wt + woff[3], b4, a4p0, pstrL4);
        } else {
            deform_lds<32, 32, 16, 5, 29, 29, 25, 25, 36, 1, 1024, 1, false, false>
                <<<g1, dim3(1024), 0, stream>>>(a2, nullptr, nullptr, off3, nullptr, wt + woff[2], b3, a3, 0);
            deform_lds< 8, 16, 16, 7, 25, 25, 19, 19, 12, 2,  768, 1, true, false>
                <<<g2, dim3(768),  0, stream>>>(a3, nullptr, nullptr, off4, nullptr, wt + woff[3], b4, a4p0, pstrL4);
        }
        deform_lds<16, 16,  8, 5, 19, 19, 15, 15, 20, 4, 1024, 2, false, false>
            <<<g1, dim3(1024), 0, stream>>>(a4p0, a4p1, nullptr, off5, nullptr, wt + woff[4], b5, a5, 0);
        deform_lds< 8,  8,  4, 3, 15, 15, 13, 13, 12, 5,  960, 1, false, false>
            <<<g1, dim3(960),  0, stream>>>(a5, nullptr, nullptr, off6, nullptr, wt + woff[5], b6, a6, 0);
    }

    fc_head<<<dim3(256), dim3(256), 0, stream>>>(a6, w7, b7, w8, b8, perm, out);
}